// Round 11
// baseline (254.778 us; speedup 1.0000x reference)
//
#include <hip/hip_runtime.h>
#include <hip/hip_fp16.h>

#define N_NODES 50000
#define N_EDGES 800000
#define F 128
#define NG 128
#define POOL_W (3*F)
#define SCAN_CHUNK 1024
#define SCAN_BLKS ((N_NODES + SCAN_CHUNK - 1) / SCAN_CHUNK)   // 49

typedef _Float16 f16x8 __attribute__((ext_vector_type(8)));
typedef float f32x2 __attribute__((ext_vector_type(2)));
typedef float f32x4 __attribute__((ext_vector_type(4)));

__device__ __forceinline__ unsigned short f2h16(float f) {
    return __half_as_ushort(__float2half_rn(f));
}
// pack two f32 -> two f16 in one u32 (v_cvt_pkrtz_f16_f32), type-safe bitcast
__device__ __forceinline__ unsigned pkh2(float a, float b) {
    auto v = __builtin_amdgcn_cvt_pkrtz(a, b);
    union { decltype(v) h; unsigned u; } t;
    t.h = v;
    return t.u;
}
// decode 4 fp8 (u32) and FMA into acc[0..3] with scalar n
__device__ __forceinline__ void fma4(float* acc, unsigned v, float n) {
    f32x2 d;
    d = __builtin_amdgcn_cvt_pk_f32_fp8((int)v, false);
    acc[0] = fmaf(n, d[0], acc[0]); acc[1] = fmaf(n, d[1], acc[1]);
    d = __builtin_amdgcn_cvt_pk_f32_fp8((int)v, true);
    acc[2] = fmaf(n, d[0], acc[2]); acc[3] = fmaf(n, d[1], acc[3]);
}
__device__ __forceinline__ unsigned char f2fp8(float f) {
    return (unsigned char)(__builtin_amdgcn_cvt_pk_fp8_f32(f, f, 0, false) & 0xFF);
}
__device__ __forceinline__ float nrm_of(unsigned u) {
    return __half2float(__ushort_as_half((unsigned short)(u & 0xFFFFu)));
}

// ---------------- init: cnt=0, pool=0, WT = f16(W^T) x3 ----------------
__global__ void k_init(int* __restrict__ cnt, float* __restrict__ pool,
                       const float* __restrict__ W0, const float* __restrict__ W1,
                       const float* __restrict__ W2, unsigned short* __restrict__ WT) {
    int i = blockIdx.x * 256 + threadIdx.x;
    if (i < N_NODES) cnt[i] = 0;
    if (i < NG * POOL_W) {
        pool[i] = 0.0f;
        int w = i >> 14, r = i & 16383;          // 3*128*128 == NG*POOL_W
        int k = r >> 7, c = r & 127;
        const float* W = (w == 0) ? W0 : (w == 1) ? W1 : W2;
        WT[(size_t)w * F * F + c * F + k] = f2h16(W[r]);
    }
}

// ---------------- hist: cnt[col]++ and record per-edge slot (2 edges/thread) --
__global__ void k_hist(const int* __restrict__ col, int* __restrict__ cnt,
                       unsigned short* __restrict__ seq) {
    int e2 = (blockIdx.x * 256 + threadIdx.x) * 2;
    if (e2 >= N_EDGES) return;
    int2 cc = *(const int2*)&col[e2];
    unsigned short s0 = (unsigned short)atomicAdd(&cnt[cc.x], 1);
    unsigned short s1 = (unsigned short)atomicAdd(&cnt[cc.y], 1);
    *(ushort2*)&seq[e2] = make_ushort2(s0, s1);
}

// ---------------- scan stage 1: per-1024-chunk sums ----------------
__global__ __launch_bounds__(256) void k_scan_red(const int* __restrict__ cnt,
                                                  int* __restrict__ part) {
    __shared__ int wsum[4];
    int i4 = blockIdx.x * SCAN_CHUNK + threadIdx.x * 4;
    int s;
    if (i4 + 3 < N_NODES) {
        int4 v = *(const int4*)&cnt[i4];
        s = v.x + v.y + v.z + v.w;
    } else {
        s = 0;
        #pragma unroll
        for (int j = 0; j < 4; ++j) if (i4 + j < N_NODES) s += cnt[i4 + j];
    }
    #pragma unroll
    for (int o = 32; o > 0; o >>= 1) s += __shfl_xor(s, o, 64);
    int lane = threadIdx.x & 63, w = threadIdx.x >> 6;
    if (lane == 0) wsum[w] = s;
    __syncthreads();
    if (threadIdx.x == 0) part[blockIdx.x] = wsum[0] + wsum[1] + wsum[2] + wsum[3];
}

// ---------------- scan stage 2 (merged): block offset + final rowptr + dis ----
__global__ __launch_bounds__(256) void k_scan_fin(const int* __restrict__ cnt,
                                                  const int* __restrict__ part,
                                                  int* __restrict__ rowptr,
                                                  float* __restrict__ dis) {
    __shared__ int wsum[4];
    __shared__ int sBase;
    int lane = threadIdx.x & 63, w = threadIdx.x >> 6;

    if (w == 0) {                         // wave 0: exclusive prefix of partials
        int v = (lane < SCAN_BLKS) ? part[lane] : 0;
        int s = v;
        #pragma unroll
        for (int o = 1; o < 64; o <<= 1) {
            int t = __shfl_up(s, o, 64);
            if (lane >= o) s += t;
        }
        if (lane == (int)blockIdx.x) sBase = s - v;   // SCAN_BLKS <= 64
    }

    int i4 = blockIdx.x * SCAN_CHUNK + threadIdx.x * 4;
    int v[4];
    #pragma unroll
    for (int j = 0; j < 4; ++j) v[j] = (i4 + j < N_NODES) ? cnt[i4 + j] : 0;
    int ts = v[0] + v[1] + v[2] + v[3];
    int incl = ts;
    #pragma unroll
    for (int o = 1; o < 64; o <<= 1) {
        int t = __shfl_up(incl, o, 64);
        if (lane >= o) incl += t;
    }
    if (lane == 63) wsum[w] = incl;
    __syncthreads();                      // covers sBase + wsum
    if (threadIdx.x == 0) {
        int a = 0;
        #pragma unroll
        for (int t = 0; t < 4; ++t) { int b = wsum[t]; wsum[t] = a; a += b; }
    }
    __syncthreads();
    int base = sBase + wsum[w] + (incl - ts);
    int pre = 0;
    #pragma unroll
    for (int j = 0; j < 4; ++j) {
        int i = i4 + j;
        if (i <= N_NODES) rowptr[i] = base + pre;
        if (i < N_NODES) dis[i] = rsqrtf((float)v[j] + 1.0f);   // +1 self loop
        pre += v[j];
    }
}

// ---------------- fill: csr[rowptr[c]+seq[e]] = (src<<16)|f16(norm), 2/thread --
__global__ void k_fill(const int* __restrict__ row, const int* __restrict__ col,
                       const unsigned short* __restrict__ seq,
                       const int* __restrict__ rowptr, const float* __restrict__ dis,
                       unsigned* __restrict__ csr) {
    int e2 = (blockIdx.x * 256 + threadIdx.x) * 2;
    if (e2 >= N_EDGES) return;
    int2 rr = *(const int2*)&row[e2];
    int2 cc = *(const int2*)&col[e2];
    ushort2 ss = *(const ushort2*)&seq[e2];
    int p0 = rowptr[cc.x] + (int)ss.x;
    csr[p0] = ((unsigned)rr.x << 16) | (unsigned)f2h16(dis[rr.x] * dis[cc.x]);
    int p1 = rowptr[cc.y] + (int)ss.y;
    csr[p1] = ((unsigned)rr.y << 16) | (unsigned)f2h16(dis[rr.y] * dis[cc.y]);
}

// ------- MFMA GEMM (f16 in, fp8 out, SPLIT halves): H0|H1 = fp8(A * W) -------
// H0 = columns 0..63 (row stride 64), H1 = columns 64..127 (row stride 64).
template <typename AIN>   // float (layer 1, converts in-reg) or ushort (f16)
__global__ __launch_bounds__(256) void k_gemm(const AIN* __restrict__ A,
                                              const unsigned short* __restrict__ WT,
                                              unsigned char* __restrict__ H0,
                                              unsigned char* __restrict__ H1) {
    __shared__ unsigned short sWT[F * 136];   // [c][k], pad 8 shorts
    for (int t = threadIdx.x; t < F * 16; t += 256) {
        int c = t >> 4, ch = t & 15;
        *(uint4*)&sWT[c * 136 + ch * 8] = *(const uint4*)&WT[(size_t)c * F + ch * 8];
    }
    __syncthreads();

    int wave = threadIdx.x >> 6, lane = threadIdx.x & 63;
    int m = lane & 15, q = lane >> 4;
    int row = blockIdx.x * 64 + wave * 16 + m;
    int arow = (row < N_NODES) ? row : (N_NODES - 1);

    f32x4 acc[8];
    #pragma unroll
    for (int c = 0; c < 8; ++c) acc[c] = 0.f;

    #pragma unroll
    for (int kk = 0; kk < 4; ++kk) {
        int k0 = kk * 32 + q * 8;
        f16x8 a;
        if constexpr (sizeof(AIN) == 4) {
            const float* ap = &A[(size_t)arow * F + k0];
            float4 a0 = *(const float4*)ap;
            float4 a1 = *(const float4*)(ap + 4);
            a[0] = (_Float16)a0.x; a[1] = (_Float16)a0.y;
            a[2] = (_Float16)a0.z; a[3] = (_Float16)a0.w;
            a[4] = (_Float16)a1.x; a[5] = (_Float16)a1.y;
            a[6] = (_Float16)a1.z; a[7] = (_Float16)a1.w;
        } else {
            a = *(const f16x8*)&A[(size_t)arow * F + k0];
        }
        #pragma unroll
        for (int c = 0; c < 8; ++c) {
            f16x8 b = *(const f16x8*)&sWT[(c * 16 + m) * 136 + k0];
            acc[c] = __builtin_amdgcn_mfma_f32_16x16x32_f16(a, b, acc[c], 0, 0, 0);
        }
    }

    int rbase = blockIdx.x * 64 + wave * 16 + q * 4;
    #pragma unroll
    for (int c = 0; c < 8; ++c) {
        unsigned char* H = (c < 4) ? H0 : H1;
        int col = (c & 3) * 16 + m;          // 0..63 within the half
        #pragma unroll
        for (int r = 0; r < 4; ++r) {
            int rr = rbase + r;
            if (rr < N_NODES) H[(size_t)rr * 64 + col] = f2fp8(acc[c][r]);
        }
    }
}

// ---------------- fused aggregate over ONE 64-feature half ----------------
// h = 3.2 MB (fits per-XCD L2). 64 lanes = 4 edge-groups x 16 lanes;
// 4 B (4 fp8 feats) per lane per gather; depth-4 prefetch; pad -> norm 0.
template <typename OUT>   // ushort (f16 -> next GEMM, full-width B) or float (x3)
__global__ __launch_bounds__(256) void k_agg(const unsigned char* __restrict__ h,
                                             const float* __restrict__ dis,
                                             const int* __restrict__ rowptr,
                                             const unsigned* __restrict__ csr,
                                             const float* __restrict__ bias,
                                             const int* __restrict__ batch,
                                             OUT* __restrict__ xout,
                                             float* __restrict__ pool,
                                             int fh) {
    int wave = threadIdx.x >> 6;
    int lane = threadIdx.x & 63;
    int g = lane >> 4;          // edge group 0..3
    int l = lane & 15;          // feature slice within half: feats [4l, 4l+4)
    int node = blockIdx.x * 4 + wave;       // grid = 12500 exact

    float acc[4] = {0.f, 0.f, 0.f, 0.f};

    int s = rowptr[node], e = rowptr[node + 1];
    int i = s + g;
    unsigned c0 = (i      < e) ? csr[i]      : 0u;
    unsigned c1 = (i + 4  < e) ? csr[i + 4]  : 0u;
    unsigned c2 = (i + 8  < e) ? csr[i + 8]  : 0u;
    unsigned c3 = (i + 12 < e) ? csr[i + 12] : 0u;
    while (i < e) {
        unsigned v0 = *(const unsigned*)(h + (size_t)(c0 >> 16) * 64 + l * 4);
        unsigned v1 = *(const unsigned*)(h + (size_t)(c1 >> 16) * 64 + l * 4);
        unsigned v2 = *(const unsigned*)(h + (size_t)(c2 >> 16) * 64 + l * 4);
        unsigned v3 = *(const unsigned*)(h + (size_t)(c3 >> 16) * 64 + l * 4);
        float n0 = nrm_of(c0), n1 = nrm_of(c1), n2 = nrm_of(c2), n3 = nrm_of(c3);
        c0 = (i + 16 < e) ? csr[i + 16] : 0u;
        c1 = (i + 20 < e) ? csr[i + 20] : 0u;
        c2 = (i + 24 < e) ? csr[i + 24] : 0u;
        c3 = (i + 28 < e) ? csr[i + 28] : 0u;
        fma4(acc, v0, n0); fma4(acc, v1, n1); fma4(acc, v2, n2); fma4(acc, v3, n3);
        i += 16;
    }

    // combine the 4 edge groups (butterfly over lane^16, lane^32)
    #pragma unroll
    for (int j = 0; j < 4; ++j) {
        acc[j] += __shfl_xor(acc[j], 16, 64);
        acc[j] += __shfl_xor(acc[j], 32, 64);
    }

    // self loop + bias + relu (all lanes; replicated across groups)
    float df = dis[node];
    unsigned sv = *(const unsigned*)(h + (size_t)node * 64 + l * 4);
    fma4(acc, sv, df * df);
    float4 ba = *(const float4*)&bias[fh * 64 + l * 4];
    acc[0] = fmaxf(acc[0] + ba.x, 0.f);
    acc[1] = fmaxf(acc[1] + ba.y, 0.f);
    acc[2] = fmaxf(acc[2] + ba.z, 0.f);
    acc[3] = fmaxf(acc[3] + ba.w, 0.f);

    if (g == 0) {
        if constexpr (sizeof(OUT) == 2) {
            uint2 o = make_uint2(pkh2(acc[0], acc[1]), pkh2(acc[2], acc[3]));
            *(uint2*)&xout[(size_t)node * F + fh * 64 + l * 4] = o;   // full-width B
        } else {
            *(float4*)&xout[(size_t)node * F + fh * 64 + l * 4] =
                make_float4(acc[0], acc[1], acc[2], acc[3]);
        }
    }

    // ---- pool: block LDS reduce (4 nodes) when same graph, else per-node ----
    __shared__ float red[4][64];
    __shared__ int gsh[4];
    if (lane == 0) gsh[wave] = batch[node];
    if (g == 0)
        *(float4*)&red[wave][l * 4] = make_float4(acc[0], acc[1], acc[2], acc[3]);
    __syncthreads();
    int g0 = gsh[0];
    bool uni = (gsh[1] == g0) & (gsh[2] == g0) & (gsh[3] == g0);
    if (uni) {
        if (threadIdx.x < 64) {
            float ssum = red[0][threadIdx.x] + red[1][threadIdx.x]
                       + red[2][threadIdx.x] + red[3][threadIdx.x];
            atomicAdd(&pool[(size_t)g0 * POOL_W + fh * 64 + threadIdx.x], ssum);
        }
    } else if (g == 0) {
        int gg = gsh[wave];
        #pragma unroll
        for (int j = 0; j < 4; ++j)
            atomicAdd(&pool[(size_t)gg * POOL_W + fh * 64 + l * 4 + j], acc[j]);
    }
}

extern "C" void kernel_launch(void* const* d_in, const int* in_sizes, int n_in,
                              void* d_out, int out_size, void* d_ws, size_t ws_size,
                              hipStream_t stream) {
    const float* x    = (const float*)d_in[0];
    const int*   erow = (const int*)d_in[1];
    const int*   ecol = erow + N_EDGES;
    const int*   batch= (const int*)d_in[2];
    const float* W0   = (const float*)d_in[3];
    const float* b0   = (const float*)d_in[4];
    const float* W1   = (const float*)d_in[5];
    const float* b1   = (const float*)d_in[6];
    const float* W2   = (const float*)d_in[7];
    const float* b2   = (const float*)d_in[8];

    float* pool = (float*)d_out;                  // [128, 384]
    float* x3   = (float*)d_out + NG * POOL_W;    // [50000, 128] fp32

    // ---- workspace carve-up (256B aligned) ----
    char* p = (char*)d_ws;
    auto carve = [&](size_t bytes) { char* q = p; p += (bytes + 255) & ~(size_t)255; return q; };
    float*          dis    = (float*)carve(N_NODES * 4);
    int*            cnt    = (int*)  carve(N_NODES * 4);
    int*            rowptr = (int*)  carve((N_NODES + 1) * 4);
    unsigned short* seq    = (unsigned short*)carve((size_t)N_EDGES * 2);
    int*            part   = (int*)  carve(SCAN_BLKS * 4);
    unsigned*       csr    = (unsigned*)carve((size_t)N_EDGES * 4);
    unsigned short* WT     = (unsigned short*)carve((size_t)3 * F * F * 2);
    unsigned char*  h0     = (unsigned char*)carve((size_t)N_NODES * 64);     // fp8 half
    unsigned char*  h1     = (unsigned char*)carve((size_t)N_NODES * 64);     // fp8 half
    unsigned short* B      = (unsigned short*)carve((size_t)N_NODES * F * 2); // f16

    const int nodeBlk  = (N_NODES + 255) / 256;       // 196
    const int edge2Blk = (N_EDGES / 2 + 255) / 256;   // 1563
    const int aggBlk   = N_NODES / 4;                 // 12500 (exact)
    const int gemmBlk  = (N_NODES + 63) / 64;         // 782

    // ---- CSR + normalization build (once, shared by 3 layers) ----
    k_init<<<nodeBlk, 256, 0, stream>>>(cnt, pool, W0, W1, W2, WT);
    k_hist<<<edge2Blk, 256, 0, stream>>>(ecol, cnt, seq);
    k_scan_red<<<SCAN_BLKS, 256, 0, stream>>>(cnt, part);
    k_scan_fin<<<SCAN_BLKS, 256, 0, stream>>>(cnt, part, rowptr, dis);
    k_fill<<<edge2Blk, 256, 0, stream>>>(erow, ecol, seq, rowptr, dis, csr);

    // ---- layer 1: x(f32) -> h0|h1(fp8) -> B(f16) ----
    k_gemm<float><<<gemmBlk, 256, 0, stream>>>(x, WT + 0 * F * F, h0, h1);
    k_agg<unsigned short><<<aggBlk, 256, 0, stream>>>(h0, dis, rowptr, csr, b0, batch, B, pool + 0 * F, 0);
    k_agg<unsigned short><<<aggBlk, 256, 0, stream>>>(h1, dis, rowptr, csr, b0, batch, B, pool + 0 * F, 1);

    // ---- layer 2: B -> h0|h1 -> B ----
    k_gemm<unsigned short><<<gemmBlk, 256, 0, stream>>>(B, WT + 1 * F * F, h0, h1);
    k_agg<unsigned short><<<aggBlk, 256, 0, stream>>>(h0, dis, rowptr, csr, b1, batch, B, pool + 1 * F, 0);
    k_agg<unsigned short><<<aggBlk, 256, 0, stream>>>(h1, dis, rowptr, csr, b1, batch, B, pool + 1 * F, 1);

    // ---- layer 3: B -> h0|h1 -> x3(f32, d_out) ----
    k_gemm<unsigned short><<<gemmBlk, 256, 0, stream>>>(B, WT + 2 * F * F, h0, h1);
    k_agg<float><<<aggBlk, 256, 0, stream>>>(h0, dis, rowptr, csr, b2, batch, x3, pool + 2 * F, 0);
    k_agg<float><<<aggBlk, 256, 0, stream>>>(h1, dis, rowptr, csr, b2, batch, x3, pool + 2 * F, 1);
}

// Round 12
// 242.931 us; speedup vs baseline: 1.0488x; 1.0488x over previous
//
#include <hip/hip_runtime.h>
#include <hip/hip_fp16.h>

#define N_NODES 50000
#define N_EDGES 800000
#define F 128
#define NG 128
#define POOL_W (3*F)
#define SCAN_CHUNK 1024
#define SCAN_BLKS ((N_NODES + SCAN_CHUNK - 1) / SCAN_CHUNK)   // 49
#define GEMM_BLKS ((N_NODES + 63) / 64)                       // 782
#define EDGE2_BLKS ((N_EDGES / 2 + 255) / 256)                // 1563

typedef _Float16 f16x8 __attribute__((ext_vector_type(8)));
typedef float f32x2 __attribute__((ext_vector_type(2)));
typedef float f32x4 __attribute__((ext_vector_type(4)));

__device__ __forceinline__ unsigned short f2h16(float f) {
    return __half_as_ushort(__float2half_rn(f));
}
// pack two f32 -> two f16 in one u32 (v_cvt_pkrtz_f16_f32), type-safe bitcast
__device__ __forceinline__ unsigned pkh2(float a, float b) {
    auto v = __builtin_amdgcn_cvt_pkrtz(a, b);
    union { decltype(v) h; unsigned u; } t;
    t.h = v;
    return t.u;
}
// decode 8 fp8 (uint2) and FMA into acc[0..7] with scalar n
__device__ __forceinline__ void fma8(float* acc, uint2 v, float n) {
    f32x2 d;
    d = __builtin_amdgcn_cvt_pk_f32_fp8((int)v.x, false);
    acc[0] = fmaf(n, d[0], acc[0]); acc[1] = fmaf(n, d[1], acc[1]);
    d = __builtin_amdgcn_cvt_pk_f32_fp8((int)v.x, true);
    acc[2] = fmaf(n, d[0], acc[2]); acc[3] = fmaf(n, d[1], acc[3]);
    d = __builtin_amdgcn_cvt_pk_f32_fp8((int)v.y, false);
    acc[4] = fmaf(n, d[0], acc[4]); acc[5] = fmaf(n, d[1], acc[5]);
    d = __builtin_amdgcn_cvt_pk_f32_fp8((int)v.y, true);
    acc[6] = fmaf(n, d[0], acc[6]); acc[7] = fmaf(n, d[1], acc[7]);
}
__device__ __forceinline__ unsigned char f2fp8(float f) {
    return (unsigned char)(__builtin_amdgcn_cvt_pk_fp8_f32(f, f, 0, false) & 0xFF);
}
__device__ __forceinline__ float nrm_of(unsigned u) {
    return __half2float(__ushort_as_half((unsigned short)(u & 0xFFFFu)));
}

// ---------------- init: cnt=0, pool=0, WT = f16(W^T) x3 ----------------
__global__ void k_init(int* __restrict__ cnt, float* __restrict__ pool,
                       const float* __restrict__ W0, const float* __restrict__ W1,
                       const float* __restrict__ W2, unsigned short* __restrict__ WT) {
    int i = blockIdx.x * 256 + threadIdx.x;
    if (i < N_NODES) cnt[i] = 0;
    if (i < NG * POOL_W) {
        pool[i] = 0.0f;
        int w = i >> 14, r = i & 16383;          // 3*128*128 == NG*POOL_W
        int k = r >> 7, c = r & 127;
        const float* W = (w == 0) ? W0 : (w == 1) ? W1 : W2;
        WT[(size_t)w * F * F + c * F + k] = f2h16(W[r]);
    }
}

// ---------------- hist: cnt[col]++ and record per-edge slot (2 edges/thread) --
__global__ void k_hist(const int* __restrict__ col, int* __restrict__ cnt,
                       unsigned short* __restrict__ seq) {
    int e2 = (blockIdx.x * 256 + threadIdx.x) * 2;
    if (e2 >= N_EDGES) return;
    int2 cc = *(const int2*)&col[e2];
    unsigned short s0 = (unsigned short)atomicAdd(&cnt[cc.x], 1);
    unsigned short s1 = (unsigned short)atomicAdd(&cnt[cc.y], 1);
    *(ushort2*)&seq[e2] = make_ushort2(s0, s1);
}

// ---------------- scan stage 1: per-1024-chunk sums ----------------
__global__ __launch_bounds__(256) void k_scan_red(const int* __restrict__ cnt,
                                                  int* __restrict__ part) {
    __shared__ int wsum[4];
    int i4 = blockIdx.x * SCAN_CHUNK + threadIdx.x * 4;
    int s;
    if (i4 + 3 < N_NODES) {
        int4 v = *(const int4*)&cnt[i4];
        s = v.x + v.y + v.z + v.w;
    } else {
        s = 0;
        #pragma unroll
        for (int j = 0; j < 4; ++j) if (i4 + j < N_NODES) s += cnt[i4 + j];
    }
    #pragma unroll
    for (int o = 32; o > 0; o >>= 1) s += __shfl_xor(s, o, 64);
    int lane = threadIdx.x & 63, w = threadIdx.x >> 6;
    if (lane == 0) wsum[w] = s;
    __syncthreads();
    if (threadIdx.x == 0) part[blockIdx.x] = wsum[0] + wsum[1] + wsum[2] + wsum[3];
}

// ---------------- scan stage 2 (merged): block offset + final rowptr + dis ----
__global__ __launch_bounds__(256) void k_scan_fin(const int* __restrict__ cnt,
                                                  const int* __restrict__ part,
                                                  int* __restrict__ rowptr,
                                                  float* __restrict__ dis) {
    __shared__ int wsum[4];
    __shared__ int sBase;
    int lane = threadIdx.x & 63, w = threadIdx.x >> 6;

    if (w == 0) {                         // wave 0: exclusive prefix of partials
        int v = (lane < SCAN_BLKS) ? part[lane] : 0;
        int s = v;
        #pragma unroll
        for (int o = 1; o < 64; o <<= 1) {
            int t = __shfl_up(s, o, 64);
            if (lane >= o) s += t;
        }
        if (lane == (int)blockIdx.x) sBase = s - v;   // SCAN_BLKS <= 64
    }

    int i4 = blockIdx.x * SCAN_CHUNK + threadIdx.x * 4;
    int v[4];
    #pragma unroll
    for (int j = 0; j < 4; ++j) v[j] = (i4 + j < N_NODES) ? cnt[i4 + j] : 0;
    int ts = v[0] + v[1] + v[2] + v[3];
    int incl = ts;
    #pragma unroll
    for (int o = 1; o < 64; o <<= 1) {
        int t = __shfl_up(incl, o, 64);
        if (lane >= o) incl += t;
    }
    if (lane == 63) wsum[w] = incl;
    __syncthreads();                      // covers sBase + wsum
    if (threadIdx.x == 0) {
        int a = 0;
        #pragma unroll
        for (int t = 0; t < 4; ++t) { int b = wsum[t]; wsum[t] = a; a += b; }
    }
    __syncthreads();
    int base = sBase + wsum[w] + (incl - ts);
    int pre = 0;
    #pragma unroll
    for (int j = 0; j < 4; ++j) {
        int i = i4 + j;
        if (i <= N_NODES) rowptr[i] = base + pre;
        if (i < N_NODES) dis[i] = rsqrtf((float)v[j] + 1.0f);   // +1 self loop
        pre += v[j];
    }
}

// ---------------- shared GEMM block body (f16 MFMA, fp8 out) ----------------
template <typename AIN>
__device__ __forceinline__ void gemm_block(int bid, const AIN* __restrict__ A,
                                           const unsigned short* __restrict__ WT,
                                           unsigned char* __restrict__ H,
                                           unsigned short* sWT) {
    for (int t = threadIdx.x; t < F * 16; t += 256) {
        int c = t >> 4, ch = t & 15;
        *(uint4*)&sWT[c * 136 + ch * 8] = *(const uint4*)&WT[(size_t)c * F + ch * 8];
    }
    __syncthreads();

    int wave = threadIdx.x >> 6, lane = threadIdx.x & 63;
    int m = lane & 15, q = lane >> 4;
    int row = bid * 64 + wave * 16 + m;
    int arow = (row < N_NODES) ? row : (N_NODES - 1);

    f32x4 acc[8];
    #pragma unroll
    for (int c = 0; c < 8; ++c) acc[c] = 0.f;

    #pragma unroll
    for (int kk = 0; kk < 4; ++kk) {
        int k0 = kk * 32 + q * 8;
        f16x8 a;
        if constexpr (sizeof(AIN) == 4) {
            const float* ap = &A[(size_t)arow * F + k0];
            float4 a0 = *(const float4*)ap;
            float4 a1 = *(const float4*)(ap + 4);
            a[0] = (_Float16)a0.x; a[1] = (_Float16)a0.y;
            a[2] = (_Float16)a0.z; a[3] = (_Float16)a0.w;
            a[4] = (_Float16)a1.x; a[5] = (_Float16)a1.y;
            a[6] = (_Float16)a1.z; a[7] = (_Float16)a1.w;
        } else {
            a = *(const f16x8*)&A[(size_t)arow * F + k0];
        }
        #pragma unroll
        for (int c = 0; c < 8; ++c) {
            f16x8 b = *(const f16x8*)&sWT[(c * 16 + m) * 136 + k0];
            acc[c] = __builtin_amdgcn_mfma_f32_16x16x32_f16(a, b, acc[c], 0, 0, 0);
        }
    }

    int rbase = bid * 64 + wave * 16 + q * 4;
    #pragma unroll
    for (int c = 0; c < 8; ++c) {
        #pragma unroll
        for (int r = 0; r < 4; ++r) {
            int rr = rbase + r;
            if (rr < N_NODES) H[(size_t)rr * F + c * 16 + m] = f2fp8(acc[c][r]);
        }
    }
}

// ---------------- GEMM layers 2/3 (f16 activations in) ----------------
__global__ __launch_bounds__(256) void k_gemm(const unsigned short* __restrict__ A,
                                              const unsigned short* __restrict__ WT,
                                              unsigned char* __restrict__ H) {
    __shared__ unsigned short sWT[F * 136];
    gemm_block<unsigned short>(blockIdx.x, A, WT, H, sWT);
}

// -------- fused: [gemm layer1 (f32 in)] || [CSR fill] in one dispatch --------
__global__ __launch_bounds__(256) void k_gemm1_fill(
        const float* __restrict__ A, const unsigned short* __restrict__ WT,
        unsigned char* __restrict__ H,
        const int* __restrict__ row, const int* __restrict__ col,
        const unsigned short* __restrict__ seq,
        const int* __restrict__ rowptr, const float* __restrict__ dis,
        unsigned* __restrict__ csr) {
    __shared__ unsigned short sWT[F * 136];
    if (blockIdx.x < GEMM_BLKS) {
        gemm_block<float>(blockIdx.x, A, WT, H, sWT);
        return;
    }
    int e2 = ((blockIdx.x - GEMM_BLKS) * 256 + threadIdx.x) * 2;
    if (e2 >= N_EDGES) return;
    int2 rr = *(const int2*)&row[e2];
    int2 cc = *(const int2*)&col[e2];
    ushort2 ss = *(const ushort2*)&seq[e2];
    int p0 = rowptr[cc.x] + (int)ss.x;
    csr[p0] = ((unsigned)rr.x << 16) | (unsigned)f2h16(dis[rr.x] * dis[cc.x]);
    int p1 = rowptr[cc.y] + (int)ss.y;
    csr[p1] = ((unsigned)rr.y << 16) | (unsigned)f2h16(dis[rr.y] * dis[cc.y]);
}

// ---------------- fused aggregate: 1024 threads = 16 waves = 16 nodes --------
// wave-per-node; 64 lanes = 4 edge-groups x 16 lanes; 8B (8 fp8) per gather;
// depth-8 prefetch; pad entries decode to (row 0, norm 0).
template <typename OUT>   // ushort (f16 -> next GEMM) or float (final x3)
__global__ __launch_bounds__(1024) void k_agg(const unsigned char* __restrict__ h,
                                              const float* __restrict__ dis,
                                              const int* __restrict__ rowptr,
                                              const unsigned* __restrict__ csr,
                                              const float* __restrict__ bias,
                                              const int* __restrict__ batch,
                                              OUT* __restrict__ xout,
                                              float* __restrict__ pool) {
    int wave = threadIdx.x >> 6;            // 0..15
    int lane = threadIdx.x & 63;
    int g = lane >> 4;          // edge group 0..3
    int l = lane & 15;          // feature slice: feats [8l, 8l+8)
    int node = blockIdx.x * 16 + wave;      // grid = 3125 exact

    float acc[8] = {0.f, 0.f, 0.f, 0.f, 0.f, 0.f, 0.f, 0.f};

    int s = rowptr[node], e = rowptr[node + 1];
    int i = s + g;
    unsigned c0 = (i      < e) ? csr[i]      : 0u;
    unsigned c1 = (i + 4  < e) ? csr[i + 4]  : 0u;
    unsigned c2 = (i + 8  < e) ? csr[i + 8]  : 0u;
    unsigned c3 = (i + 12 < e) ? csr[i + 12] : 0u;
    unsigned c4 = (i + 16 < e) ? csr[i + 16] : 0u;
    unsigned c5 = (i + 20 < e) ? csr[i + 20] : 0u;
    unsigned c6 = (i + 24 < e) ? csr[i + 24] : 0u;
    unsigned c7 = (i + 28 < e) ? csr[i + 28] : 0u;
    while (i < e) {
        uint2 v0 = *(const uint2*)(h + (size_t)(c0 >> 16) * F + l * 8);
        uint2 v1 = *(const uint2*)(h + (size_t)(c1 >> 16) * F + l * 8);
        uint2 v2 = *(const uint2*)(h + (size_t)(c2 >> 16) * F + l * 8);
        uint2 v3 = *(const uint2*)(h + (size_t)(c3 >> 16) * F + l * 8);
        uint2 v4 = *(const uint2*)(h + (size_t)(c4 >> 16) * F + l * 8);
        uint2 v5 = *(const uint2*)(h + (size_t)(c5 >> 16) * F + l * 8);
        uint2 v6 = *(const uint2*)(h + (size_t)(c6 >> 16) * F + l * 8);
        uint2 v7 = *(const uint2*)(h + (size_t)(c7 >> 16) * F + l * 8);
        float n0 = nrm_of(c0), n1 = nrm_of(c1), n2 = nrm_of(c2), n3 = nrm_of(c3);
        float n4 = nrm_of(c4), n5 = nrm_of(c5), n6 = nrm_of(c6), n7 = nrm_of(c7);
        c0 = (i + 32 < e) ? csr[i + 32] : 0u;
        c1 = (i + 36 < e) ? csr[i + 36] : 0u;
        c2 = (i + 40 < e) ? csr[i + 40] : 0u;
        c3 = (i + 44 < e) ? csr[i + 44] : 0u;
        c4 = (i + 48 < e) ? csr[i + 48] : 0u;
        c5 = (i + 52 < e) ? csr[i + 52] : 0u;
        c6 = (i + 56 < e) ? csr[i + 56] : 0u;
        c7 = (i + 60 < e) ? csr[i + 60] : 0u;
        fma8(acc, v0, n0); fma8(acc, v1, n1); fma8(acc, v2, n2); fma8(acc, v3, n3);
        fma8(acc, v4, n4); fma8(acc, v5, n5); fma8(acc, v6, n6); fma8(acc, v7, n7);
        i += 32;
    }

    // combine the 4 edge groups (butterfly over lane^16, lane^32)
    #pragma unroll
    for (int j = 0; j < 8; ++j) {
        acc[j] += __shfl_xor(acc[j], 16, 64);
        acc[j] += __shfl_xor(acc[j], 32, 64);
    }

    // self loop + bias + relu (all lanes; replicated across groups)
    float df = dis[node];
    uint2 sv = *(const uint2*)(h + (size_t)node * F + l * 8);
    fma8(acc, sv, df * df);
    float4 ba = *(const float4*)&bias[l * 8];
    float4 bb = *(const float4*)&bias[l * 8 + 4];
    acc[0] = fmaxf(acc[0] + ba.x, 0.f);
    acc[1] = fmaxf(acc[1] + ba.y, 0.f);
    acc[2] = fmaxf(acc[2] + ba.z, 0.f);
    acc[3] = fmaxf(acc[3] + ba.w, 0.f);
    acc[4] = fmaxf(acc[4] + bb.x, 0.f);
    acc[5] = fmaxf(acc[5] + bb.y, 0.f);
    acc[6] = fmaxf(acc[6] + bb.z, 0.f);
    acc[7] = fmaxf(acc[7] + bb.w, 0.f);

    if (g == 0) {
        if constexpr (sizeof(OUT) == 2) {
            uint4 o;
            o.x = pkh2(acc[0], acc[1]);
            o.y = pkh2(acc[2], acc[3]);
            o.z = pkh2(acc[4], acc[5]);
            o.w = pkh2(acc[6], acc[7]);
            *(uint4*)&xout[(size_t)node * F + l * 8] = o;
        } else {
            *(float4*)&xout[(size_t)node * F + l * 8] =
                make_float4(acc[0], acc[1], acc[2], acc[3]);
            *(float4*)&xout[(size_t)node * F + l * 8 + 4] =
                make_float4(acc[4], acc[5], acc[6], acc[7]);
        }
    }

    // ---- pool: block LDS reduce (16 nodes) when same graph, else per-node ----
    __shared__ float red[16][F];
    __shared__ int gsh[16];
    if (lane == 0) gsh[wave] = batch[node];
    if (g == 0) {
        *(float4*)&red[wave][l * 8]     = make_float4(acc[0], acc[1], acc[2], acc[3]);
        *(float4*)&red[wave][l * 8 + 4] = make_float4(acc[4], acc[5], acc[6], acc[7]);
    }
    __syncthreads();
    int g0 = gsh[0];
    bool uni = true;
    #pragma unroll
    for (int t = 1; t < 16; ++t) uni &= (gsh[t] == g0);
    if (uni) {
        if (threadIdx.x < F) {
            float ssum = 0.f;
            #pragma unroll
            for (int t = 0; t < 16; ++t) ssum += red[t][threadIdx.x];
            atomicAdd(&pool[(size_t)g0 * POOL_W + threadIdx.x], ssum);
        }
    } else if (g == 0) {
        int gg = gsh[wave];
        #pragma unroll
        for (int j = 0; j < 8; ++j)
            atomicAdd(&pool[(size_t)gg * POOL_W + l * 8 + j], acc[j]);
    }
}

extern "C" void kernel_launch(void* const* d_in, const int* in_sizes, int n_in,
                              void* d_out, int out_size, void* d_ws, size_t ws_size,
                              hipStream_t stream) {
    const float* x    = (const float*)d_in[0];
    const int*   erow = (const int*)d_in[1];
    const int*   ecol = erow + N_EDGES;
    const int*   batch= (const int*)d_in[2];
    const float* W0   = (const float*)d_in[3];
    const float* b0   = (const float*)d_in[4];
    const float* W1   = (const float*)d_in[5];
    const float* b1   = (const float*)d_in[6];
    const float* W2   = (const float*)d_in[7];
    const float* b2   = (const float*)d_in[8];

    float* pool = (float*)d_out;                  // [128, 384]
    float* x3   = (float*)d_out + NG * POOL_W;    // [50000, 128] fp32

    // ---- workspace carve-up (256B aligned) ----
    char* p = (char*)d_ws;
    auto carve = [&](size_t bytes) { char* q = p; p += (bytes + 255) & ~(size_t)255; return q; };
    float*          dis    = (float*)carve(N_NODES * 4);
    int*            cnt    = (int*)  carve(N_NODES * 4);
    int*            rowptr = (int*)  carve((N_NODES + 1) * 4);
    unsigned short* seq    = (unsigned short*)carve((size_t)N_EDGES * 2);
    int*            part   = (int*)  carve(SCAN_BLKS * 4);
    unsigned*       csr    = (unsigned*)carve((size_t)N_EDGES * 4);
    unsigned short* WT     = (unsigned short*)carve((size_t)3 * F * F * 2);
    unsigned char*  h      = (unsigned char*)carve((size_t)N_NODES * F);      // fp8
    unsigned short* B      = (unsigned short*)carve((size_t)N_NODES * F * 2); // f16

    const int nodeBlk  = (N_NODES + 255) / 256;       // 196
    const int aggBlk   = N_NODES / 16;                // 3125 (exact)

    // ---- CSR build; layer-1 GEMM fused into the fill dispatch ----
    k_init<<<nodeBlk, 256, 0, stream>>>(cnt, pool, W0, W1, W2, WT);
    k_hist<<<EDGE2_BLKS, 256, 0, stream>>>(ecol, cnt, seq);
    k_scan_red<<<SCAN_BLKS, 256, 0, stream>>>(cnt, part);
    k_scan_fin<<<SCAN_BLKS, 256, 0, stream>>>(cnt, part, rowptr, dis);
    k_gemm1_fill<<<GEMM_BLKS + EDGE2_BLKS, 256, 0, stream>>>(
        x, WT + 0 * F * F, h, erow, ecol, seq, rowptr, dis, csr);

    // ---- layer 1 aggregate: h(fp8) -> B(f16) ----
    k_agg<unsigned short><<<aggBlk, 1024, 0, stream>>>(h, dis, rowptr, csr, b0, batch, B, pool + 0 * F);

    // ---- layer 2: B -> h -> B ----
    k_gemm<<<GEMM_BLKS, 256, 0, stream>>>(B, WT + 1 * F * F, h);
    k_agg<unsigned short><<<aggBlk, 1024, 0, stream>>>(h, dis, rowptr, csr, b1, batch, B, pool + 1 * F);

    // ---- layer 3: B -> h -> x3(f32, d_out) ----
    k_gemm<<<GEMM_BLKS, 256, 0, stream>>>(B, WT + 2 * F * F, h);
    k_agg<float><<<aggBlk, 1024, 0, stream>>>(h, dis, rowptr, csr, b2, batch, x3, pool + 2 * F);
}

// Round 13
// 237.601 us; speedup vs baseline: 1.0723x; 1.0224x over previous
//
#include <hip/hip_runtime.h>
#include <hip/hip_fp16.h>

#define N_NODES 50000
#define N_EDGES 800000
#define F 128
#define NG 128
#define POOL_W (3*F)
#define SCAN_CHUNK 1024
#define SCAN_BLKS ((N_NODES + SCAN_CHUNK - 1) / SCAN_CHUNK)   // 49
#define GEMM_BLKS ((N_NODES + 63) / 64)                       // 782
#define EDGE2_BLKS ((N_EDGES / 2 + 255) / 256)                // 1563

typedef _Float16 f16x8 __attribute__((ext_vector_type(8)));
typedef float f32x2 __attribute__((ext_vector_type(2)));
typedef float f32x4 __attribute__((ext_vector_type(4)));

__device__ __forceinline__ unsigned short f2h16(float f) {
    return __half_as_ushort(__float2half_rn(f));
}
// pack two f32 -> two f16 in one u32 (v_cvt_pkrtz_f16_f32), type-safe bitcast
__device__ __forceinline__ unsigned pkh2(float a, float b) {
    auto v = __builtin_amdgcn_cvt_pkrtz(a, b);
    union { decltype(v) h; unsigned u; } t;
    t.h = v;
    return t.u;
}
// decode 8 fp8 (u64) and FMA into acc[0..7] with scalar n
__device__ __forceinline__ void fma8(float* acc, unsigned long long v, float n) {
    unsigned lo = (unsigned)v, hi = (unsigned)(v >> 32);
    f32x2 d;
    d = __builtin_amdgcn_cvt_pk_f32_fp8((int)lo, false);
    acc[0] = fmaf(n, d[0], acc[0]); acc[1] = fmaf(n, d[1], acc[1]);
    d = __builtin_amdgcn_cvt_pk_f32_fp8((int)lo, true);
    acc[2] = fmaf(n, d[0], acc[2]); acc[3] = fmaf(n, d[1], acc[3]);
    d = __builtin_amdgcn_cvt_pk_f32_fp8((int)hi, false);
    acc[4] = fmaf(n, d[0], acc[4]); acc[5] = fmaf(n, d[1], acc[5]);
    d = __builtin_amdgcn_cvt_pk_f32_fp8((int)hi, true);
    acc[6] = fmaf(n, d[0], acc[6]); acc[7] = fmaf(n, d[1], acc[7]);
}
__device__ __forceinline__ unsigned char f2fp8(float f) {
    return (unsigned char)(__builtin_amdgcn_cvt_pk_fp8_f32(f, f, 0, false) & 0xFF);
}
__device__ __forceinline__ float nrm_of(unsigned u) {
    return __half2float(__ushort_as_half((unsigned short)(u & 0xFFFFu)));
}

// ---------------- init: cnt=0, pool=0, WT = f16(W^T) x3 ----------------
__global__ void k_init(int* __restrict__ cnt, float* __restrict__ pool,
                       const float* __restrict__ W0, const float* __restrict__ W1,
                       const float* __restrict__ W2, unsigned short* __restrict__ WT) {
    int i = blockIdx.x * 256 + threadIdx.x;
    if (i < N_NODES) cnt[i] = 0;
    if (i < NG * POOL_W) {
        pool[i] = 0.0f;
        int w = i >> 14, r = i & 16383;          // 3*128*128 == NG*POOL_W
        int k = r >> 7, c = r & 127;
        const float* W = (w == 0) ? W0 : (w == 1) ? W1 : W2;
        WT[(size_t)w * F * F + c * F + k] = f2h16(W[r]);
    }
}

// ---------------- hist: cnt[col]++ and record per-edge slot (2 edges/thread) --
__global__ void k_hist(const int* __restrict__ col, int* __restrict__ cnt,
                       unsigned short* __restrict__ seq) {
    int e2 = (blockIdx.x * 256 + threadIdx.x) * 2;
    if (e2 >= N_EDGES) return;
    int2 cc = *(const int2*)&col[e2];
    unsigned short s0 = (unsigned short)atomicAdd(&cnt[cc.x], 1);
    unsigned short s1 = (unsigned short)atomicAdd(&cnt[cc.y], 1);
    *(ushort2*)&seq[e2] = make_ushort2(s0, s1);
}

// ---------------- scan stage 1: per-1024-chunk sums ----------------
__global__ __launch_bounds__(256) void k_scan_red(const int* __restrict__ cnt,
                                                  int* __restrict__ part) {
    __shared__ int wsum[4];
    int i4 = blockIdx.x * SCAN_CHUNK + threadIdx.x * 4;
    int s;
    if (i4 + 3 < N_NODES) {
        int4 v = *(const int4*)&cnt[i4];
        s = v.x + v.y + v.z + v.w;
    } else {
        s = 0;
        #pragma unroll
        for (int j = 0; j < 4; ++j) if (i4 + j < N_NODES) s += cnt[i4 + j];
    }
    #pragma unroll
    for (int o = 32; o > 0; o >>= 1) s += __shfl_xor(s, o, 64);
    int lane = threadIdx.x & 63, w = threadIdx.x >> 6;
    if (lane == 0) wsum[w] = s;
    __syncthreads();
    if (threadIdx.x == 0) part[blockIdx.x] = wsum[0] + wsum[1] + wsum[2] + wsum[3];
}

// ---------------- scan stage 2 (merged): block offset + final rowptr + dis ----
__global__ __launch_bounds__(256) void k_scan_fin(const int* __restrict__ cnt,
                                                  const int* __restrict__ part,
                                                  int* __restrict__ rowptr,
                                                  float* __restrict__ dis) {
    __shared__ int wsum[4];
    __shared__ int sBase;
    int lane = threadIdx.x & 63, w = threadIdx.x >> 6;

    if (w == 0) {                         // wave 0: exclusive prefix of partials
        int v = (lane < SCAN_BLKS) ? part[lane] : 0;
        int s = v;
        #pragma unroll
        for (int o = 1; o < 64; o <<= 1) {
            int t = __shfl_up(s, o, 64);
            if (lane >= o) s += t;
        }
        if (lane == (int)blockIdx.x) sBase = s - v;   // SCAN_BLKS <= 64
    }

    int i4 = blockIdx.x * SCAN_CHUNK + threadIdx.x * 4;
    int v[4];
    #pragma unroll
    for (int j = 0; j < 4; ++j) v[j] = (i4 + j < N_NODES) ? cnt[i4 + j] : 0;
    int ts = v[0] + v[1] + v[2] + v[3];
    int incl = ts;
    #pragma unroll
    for (int o = 1; o < 64; o <<= 1) {
        int t = __shfl_up(incl, o, 64);
        if (lane >= o) incl += t;
    }
    if (lane == 63) wsum[w] = incl;
    __syncthreads();                      // covers sBase + wsum
    if (threadIdx.x == 0) {
        int a = 0;
        #pragma unroll
        for (int t = 0; t < 4; ++t) { int b = wsum[t]; wsum[t] = a; a += b; }
    }
    __syncthreads();
    int base = sBase + wsum[w] + (incl - ts);
    int pre = 0;
    #pragma unroll
    for (int j = 0; j < 4; ++j) {
        int i = i4 + j;
        if (i <= N_NODES) rowptr[i] = base + pre;
        if (i < N_NODES) dis[i] = rsqrtf((float)v[j] + 1.0f);   // +1 self loop
        pre += v[j];
    }
}

// ---------------- shared GEMM block body (f16 MFMA, fp8 out) ----------------
template <typename AIN>
__device__ __forceinline__ void gemm_block(int bid, const AIN* __restrict__ A,
                                           const unsigned short* __restrict__ WT,
                                           unsigned char* __restrict__ H,
                                           unsigned short* sWT) {
    for (int t = threadIdx.x; t < F * 16; t += 256) {
        int c = t >> 4, ch = t & 15;
        *(uint4*)&sWT[c * 136 + ch * 8] = *(const uint4*)&WT[(size_t)c * F + ch * 8];
    }
    __syncthreads();

    int wave = threadIdx.x >> 6, lane = threadIdx.x & 63;
    int m = lane & 15, q = lane >> 4;
    int row = bid * 64 + wave * 16 + m;
    int arow = (row < N_NODES) ? row : (N_NODES - 1);

    f32x4 acc[8];
    #pragma unroll
    for (int c = 0; c < 8; ++c) acc[c] = 0.f;

    #pragma unroll
    for (int kk = 0; kk < 4; ++kk) {
        int k0 = kk * 32 + q * 8;
        f16x8 a;
        if constexpr (sizeof(AIN) == 4) {
            const float* ap = &A[(size_t)arow * F + k0];
            float4 a0 = *(const float4*)ap;
            float4 a1 = *(const float4*)(ap + 4);
            a[0] = (_Float16)a0.x; a[1] = (_Float16)a0.y;
            a[2] = (_Float16)a0.z; a[3] = (_Float16)a0.w;
            a[4] = (_Float16)a1.x; a[5] = (_Float16)a1.y;
            a[6] = (_Float16)a1.z; a[7] = (_Float16)a1.w;
        } else {
            a = *(const f16x8*)&A[(size_t)arow * F + k0];
        }
        #pragma unroll
        for (int c = 0; c < 8; ++c) {
            f16x8 b = *(const f16x8*)&sWT[(c * 16 + m) * 136 + k0];
            acc[c] = __builtin_amdgcn_mfma_f32_16x16x32_f16(a, b, acc[c], 0, 0, 0);
        }
    }

    int rbase = bid * 64 + wave * 16 + q * 4;
    #pragma unroll
    for (int c = 0; c < 8; ++c) {
        #pragma unroll
        for (int r = 0; r < 4; ++r) {
            int rr = rbase + r;
            if (rr < N_NODES) H[(size_t)rr * F + c * 16 + m] = f2fp8(acc[c][r]);
        }
    }
}

// ---------------- GEMM layers 2/3 (f16 activations in) ----------------
__global__ __launch_bounds__(256) void k_gemm(const unsigned short* __restrict__ A,
                                              const unsigned short* __restrict__ WT,
                                              unsigned char* __restrict__ H) {
    __shared__ unsigned short sWT[F * 136];
    gemm_block<unsigned short>(blockIdx.x, A, WT, H, sWT);
}

// -------- fused: [gemm layer1 (f32 in)] || [CSR fill] in one dispatch --------
__global__ __launch_bounds__(256) void k_gemm1_fill(
        const float* __restrict__ A, const unsigned short* __restrict__ WT,
        unsigned char* __restrict__ H,
        const int* __restrict__ row, const int* __restrict__ col,
        const unsigned short* __restrict__ seq,
        const int* __restrict__ rowptr, const float* __restrict__ dis,
        unsigned* __restrict__ csr) {
    __shared__ unsigned short sWT[F * 136];
    if (blockIdx.x < GEMM_BLKS) {
        gemm_block<float>(blockIdx.x, A, WT, H, sWT);
        return;
    }
    int e2 = ((blockIdx.x - GEMM_BLKS) * 256 + threadIdx.x) * 2;
    if (e2 >= N_EDGES) return;
    int2 rr = *(const int2*)&row[e2];
    int2 cc = *(const int2*)&col[e2];
    ushort2 ss = *(const ushort2*)&seq[e2];
    int p0 = rowptr[cc.x] + (int)ss.x;
    csr[p0] = ((unsigned)rr.x << 16) | (unsigned)f2h16(dis[rr.x] * dis[cc.x]);
    int p1 = rowptr[cc.y] + (int)ss.y;
    csr[p1] = ((unsigned)rr.y << 16) | (unsigned)f2h16(dis[rr.y] * dis[cc.y]);
}

// ---------------- fused aggregate: wave-per-node CSR gather, fp8 rows ---------
// 64 lanes = 4 edge-groups x 16 lanes; 8 B (8 fp8 feats) per lane per gather.
// 8 edges in flight per group (depth 8, stride 32); pad entries -> norm 0.
// Nontemporal loads on h/csr: single-use streams, skip L1.
template <typename OUT>   // ushort (f16 -> next GEMM) or float (final x3)
__global__ __launch_bounds__(256) void k_agg(const unsigned char* __restrict__ h,
                                             const float* __restrict__ dis,
                                             const int* __restrict__ rowptr,
                                             const unsigned* __restrict__ csr,
                                             const float* __restrict__ bias,
                                             const int* __restrict__ batch,
                                             OUT* __restrict__ xout,
                                             float* __restrict__ pool) {
    int wave = threadIdx.x >> 6;
    int lane = threadIdx.x & 63;
    int g = lane >> 4;          // edge group 0..3
    int l = lane & 15;          // feature slice: feats [8l, 8l+8)
    int node = blockIdx.x * 4 + wave;       // grid = 12500 exact

    float acc[8] = {0.f, 0.f, 0.f, 0.f, 0.f, 0.f, 0.f, 0.f};

    int s = rowptr[node], e = rowptr[node + 1];
    int i = s + g;
    unsigned c0 = (i      < e) ? __builtin_nontemporal_load(&csr[i])      : 0u;
    unsigned c1 = (i + 4  < e) ? __builtin_nontemporal_load(&csr[i + 4])  : 0u;
    unsigned c2 = (i + 8  < e) ? __builtin_nontemporal_load(&csr[i + 8])  : 0u;
    unsigned c3 = (i + 12 < e) ? __builtin_nontemporal_load(&csr[i + 12]) : 0u;
    unsigned c4 = (i + 16 < e) ? __builtin_nontemporal_load(&csr[i + 16]) : 0u;
    unsigned c5 = (i + 20 < e) ? __builtin_nontemporal_load(&csr[i + 20]) : 0u;
    unsigned c6 = (i + 24 < e) ? __builtin_nontemporal_load(&csr[i + 24]) : 0u;
    unsigned c7 = (i + 28 < e) ? __builtin_nontemporal_load(&csr[i + 28]) : 0u;
    while (i < e) {
        unsigned long long v0 = __builtin_nontemporal_load(
            (const unsigned long long*)(h + (size_t)(c0 >> 16) * F + l * 8));
        unsigned long long v1 = __builtin_nontemporal_load(
            (const unsigned long long*)(h + (size_t)(c1 >> 16) * F + l * 8));
        unsigned long long v2 = __builtin_nontemporal_load(
            (const unsigned long long*)(h + (size_t)(c2 >> 16) * F + l * 8));
        unsigned long long v3 = __builtin_nontemporal_load(
            (const unsigned long long*)(h + (size_t)(c3 >> 16) * F + l * 8));
        unsigned long long v4 = __builtin_nontemporal_load(
            (const unsigned long long*)(h + (size_t)(c4 >> 16) * F + l * 8));
        unsigned long long v5 = __builtin_nontemporal_load(
            (const unsigned long long*)(h + (size_t)(c5 >> 16) * F + l * 8));
        unsigned long long v6 = __builtin_nontemporal_load(
            (const unsigned long long*)(h + (size_t)(c6 >> 16) * F + l * 8));
        unsigned long long v7 = __builtin_nontemporal_load(
            (const unsigned long long*)(h + (size_t)(c7 >> 16) * F + l * 8));
        float n0 = nrm_of(c0), n1 = nrm_of(c1), n2 = nrm_of(c2), n3 = nrm_of(c3);
        float n4 = nrm_of(c4), n5 = nrm_of(c5), n6 = nrm_of(c6), n7 = nrm_of(c7);
        c0 = (i + 32 < e) ? __builtin_nontemporal_load(&csr[i + 32]) : 0u;
        c1 = (i + 36 < e) ? __builtin_nontemporal_load(&csr[i + 36]) : 0u;
        c2 = (i + 40 < e) ? __builtin_nontemporal_load(&csr[i + 40]) : 0u;
        c3 = (i + 44 < e) ? __builtin_nontemporal_load(&csr[i + 44]) : 0u;
        c4 = (i + 48 < e) ? __builtin_nontemporal_load(&csr[i + 48]) : 0u;
        c5 = (i + 52 < e) ? __builtin_nontemporal_load(&csr[i + 52]) : 0u;
        c6 = (i + 56 < e) ? __builtin_nontemporal_load(&csr[i + 56]) : 0u;
        c7 = (i + 60 < e) ? __builtin_nontemporal_load(&csr[i + 60]) : 0u;
        fma8(acc, v0, n0); fma8(acc, v1, n1); fma8(acc, v2, n2); fma8(acc, v3, n3);
        fma8(acc, v4, n4); fma8(acc, v5, n5); fma8(acc, v6, n6); fma8(acc, v7, n7);
        i += 32;
    }

    // combine the 4 edge groups (butterfly over lane^16, lane^32)
    #pragma unroll
    for (int j = 0; j < 8; ++j) {
        acc[j] += __shfl_xor(acc[j], 16, 64);
        acc[j] += __shfl_xor(acc[j], 32, 64);
    }

    // self loop + bias + relu (all lanes; replicated across groups)
    float df = dis[node];
    unsigned long long sv = *(const unsigned long long*)(h + (size_t)node * F + l * 8);
    fma8(acc, sv, df * df);
    float4 ba = *(const float4*)&bias[l * 8];
    float4 bb = *(const float4*)&bias[l * 8 + 4];
    acc[0] = fmaxf(acc[0] + ba.x, 0.f);
    acc[1] = fmaxf(acc[1] + ba.y, 0.f);
    acc[2] = fmaxf(acc[2] + ba.z, 0.f);
    acc[3] = fmaxf(acc[3] + ba.w, 0.f);
    acc[4] = fmaxf(acc[4] + bb.x, 0.f);
    acc[5] = fmaxf(acc[5] + bb.y, 0.f);
    acc[6] = fmaxf(acc[6] + bb.z, 0.f);
    acc[7] = fmaxf(acc[7] + bb.w, 0.f);

    if (g == 0) {
        if constexpr (sizeof(OUT) == 2) {
            uint4 o;
            o.x = pkh2(acc[0], acc[1]);
            o.y = pkh2(acc[2], acc[3]);
            o.z = pkh2(acc[4], acc[5]);
            o.w = pkh2(acc[6], acc[7]);
            *(uint4*)&xout[(size_t)node * F + l * 8] = o;
        } else {
            *(float4*)&xout[(size_t)node * F + l * 8] =
                make_float4(acc[0], acc[1], acc[2], acc[3]);
            *(float4*)&xout[(size_t)node * F + l * 8 + 4] =
                make_float4(acc[4], acc[5], acc[6], acc[7]);
        }
    }

    // ---- pool: block LDS reduce (4 nodes) when same graph, else per-node ----
    __shared__ float red[4][F];
    __shared__ int gsh[4];
    if (lane == 0) gsh[wave] = batch[node];
    if (g == 0) {
        *(float4*)&red[wave][l * 8]     = make_float4(acc[0], acc[1], acc[2], acc[3]);
        *(float4*)&red[wave][l * 8 + 4] = make_float4(acc[4], acc[5], acc[6], acc[7]);
    }
    __syncthreads();
    int g0 = gsh[0];
    bool uni = (gsh[1] == g0) & (gsh[2] == g0) & (gsh[3] == g0);
    if (uni) {
        if (threadIdx.x < F) {
            float ssum = red[0][threadIdx.x] + red[1][threadIdx.x]
                       + red[2][threadIdx.x] + red[3][threadIdx.x];
            atomicAdd(&pool[(size_t)g0 * POOL_W + threadIdx.x], ssum);
        }
    } else if (g == 0) {
        int gg = gsh[wave];
        #pragma unroll
        for (int j = 0; j < 8; ++j)
            atomicAdd(&pool[(size_t)gg * POOL_W + l * 8 + j], acc[j]);
    }
}

extern "C" void kernel_launch(void* const* d_in, const int* in_sizes, int n_in,
                              void* d_out, int out_size, void* d_ws, size_t ws_size,
                              hipStream_t stream) {
    const float* x    = (const float*)d_in[0];
    const int*   erow = (const int*)d_in[1];
    const int*   ecol = erow + N_EDGES;
    const int*   batch= (const int*)d_in[2];
    const float* W0   = (const float*)d_in[3];
    const float* b0   = (const float*)d_in[4];
    const float* W1   = (const float*)d_in[5];
    const float* b1   = (const float*)d_in[6];
    const float* W2   = (const float*)d_in[7];
    const float* b2   = (const float*)d_in[8];

    float* pool = (float*)d_out;                  // [128, 384]
    float* x3   = (float*)d_out + NG * POOL_W;    // [50000, 128] fp32

    // ---- workspace carve-up (256B aligned) ----
    char* p = (char*)d_ws;
    auto carve = [&](size_t bytes) { char* q = p; p += (bytes + 255) & ~(size_t)255; return q; };
    float*          dis    = (float*)carve(N_NODES * 4);
    int*            cnt    = (int*)  carve(N_NODES * 4);
    int*            rowptr = (int*)  carve((N_NODES + 1) * 4);
    unsigned short* seq    = (unsigned short*)carve((size_t)N_EDGES * 2);
    int*            part   = (int*)  carve(SCAN_BLKS * 4);
    unsigned*       csr    = (unsigned*)carve((size_t)N_EDGES * 4);
    unsigned short* WT     = (unsigned short*)carve((size_t)3 * F * F * 2);
    unsigned char*  h      = (unsigned char*)carve((size_t)N_NODES * F);      // fp8
    unsigned short* B      = (unsigned short*)carve((size_t)N_NODES * F * 2); // f16

    const int nodeBlk  = (N_NODES + 255) / 256;       // 196
    const int aggBlk   = N_NODES / 4;                 // 12500 (exact)

    // ---- CSR build; layer-1 GEMM fused into the fill dispatch ----
    k_init<<<nodeBlk, 256, 0, stream>>>(cnt, pool, W0, W1, W2, WT);
    k_hist<<<EDGE2_BLKS, 256, 0, stream>>>(ecol, cnt, seq);
    k_scan_red<<<SCAN_BLKS, 256, 0, stream>>>(cnt, part);
    k_scan_fin<<<SCAN_BLKS, 256, 0, stream>>>(cnt, part, rowptr, dis);
    k_gemm1_fill<<<GEMM_BLKS + EDGE2_BLKS, 256, 0, stream>>>(
        x, WT + 0 * F * F, h, erow, ecol, seq, rowptr, dis, csr);

    // ---- layer 1 aggregate: h(fp8) -> B(f16) ----
    k_agg<unsigned short><<<aggBlk, 256, 0, stream>>>(h, dis, rowptr, csr, b0, batch, B, pool + 0 * F);

    // ---- layer 2: B -> h -> B ----
    k_gemm<<<GEMM_BLKS, 256, 0, stream>>>(B, WT + 1 * F * F, h);
    k_agg<unsigned short><<<aggBlk, 256, 0, stream>>>(h, dis, rowptr, csr, b1, batch, B, pool + 1 * F);

    // ---- layer 3: B -> h -> x3(f32, d_out) ----
    k_gemm<<<GEMM_BLKS, 256, 0, stream>>>(B, WT + 2 * F * F, h);
    k_agg<float><<<aggBlk, 256, 0, stream>>>(h, dis, rowptr, csr, b2, batch, x3, pool + 2 * F);
}

// Round 14
// 214.236 us; speedup vs baseline: 1.1892x; 1.1091x over previous
//
#include <hip/hip_runtime.h>
#include <hip/hip_fp16.h>

#define N_NODES 50000
#define N_EDGES 800000
#define F 128
#define NG 128
#define POOL_W (3*F)
#define SCAN_CHUNK 1024
#define SCAN_BLKS ((N_NODES + SCAN_CHUNK - 1) / SCAN_CHUNK)   // 49
#define GEMM_BLKS ((N_NODES + 63) / 64)                       // 782
#define EDGE2_BLKS ((N_EDGES / 2 + 255) / 256)                // 1563

typedef _Float16 f16x8 __attribute__((ext_vector_type(8)));
typedef float f32x2 __attribute__((ext_vector_type(2)));
typedef float f32x4 __attribute__((ext_vector_type(4)));

__device__ __forceinline__ unsigned short f2h16(float f) {
    return __half_as_ushort(__float2half_rn(f));
}
// pack two f32 -> two f16 in one u32 (v_cvt_pkrtz_f16_f32), type-safe bitcast
__device__ __forceinline__ unsigned pkh2(float a, float b) {
    auto v = __builtin_amdgcn_cvt_pkrtz(a, b);
    union { decltype(v) h; unsigned u; } t;
    t.h = v;
    return t.u;
}
// decode 8 fp8 (u64) and FMA into acc[0..7] with scalar n
__device__ __forceinline__ void fma8(float* acc, unsigned long long v, float n) {
    unsigned lo = (unsigned)v, hi = (unsigned)(v >> 32);
    f32x2 d;
    d = __builtin_amdgcn_cvt_pk_f32_fp8((int)lo, false);
    acc[0] = fmaf(n, d[0], acc[0]); acc[1] = fmaf(n, d[1], acc[1]);
    d = __builtin_amdgcn_cvt_pk_f32_fp8((int)lo, true);
    acc[2] = fmaf(n, d[0], acc[2]); acc[3] = fmaf(n, d[1], acc[3]);
    d = __builtin_amdgcn_cvt_pk_f32_fp8((int)hi, false);
    acc[4] = fmaf(n, d[0], acc[4]); acc[5] = fmaf(n, d[1], acc[5]);
    d = __builtin_amdgcn_cvt_pk_f32_fp8((int)hi, true);
    acc[6] = fmaf(n, d[0], acc[6]); acc[7] = fmaf(n, d[1], acc[7]);
}
__device__ __forceinline__ unsigned char f2fp8(float f) {
    return (unsigned char)(__builtin_amdgcn_cvt_pk_fp8_f32(f, f, 0, false) & 0xFF);
}
__device__ __forceinline__ float nrm_of(unsigned u) {
    return __half2float(__ushort_as_half((unsigned short)(u & 0xFFFFu)));
}

// ---------------- init: cnt=0, pool=0, WT = f16(W^T) x3 ----------------
__global__ void k_init(int* __restrict__ cnt, float* __restrict__ pool,
                       const float* __restrict__ W0, const float* __restrict__ W1,
                       const float* __restrict__ W2, unsigned short* __restrict__ WT) {
    int i = blockIdx.x * 256 + threadIdx.x;
    if (i < N_NODES) cnt[i] = 0;
    if (i < NG * POOL_W) {
        pool[i] = 0.0f;
        int w = i >> 14, r = i & 16383;          // 3*128*128 == NG*POOL_W
        int k = r >> 7, c = r & 127;
        const float* W = (w == 0) ? W0 : (w == 1) ? W1 : W2;
        WT[(size_t)w * F * F + c * F + k] = f2h16(W[r]);
    }
}

// ---------------- hist: cnt[col]++ and record per-edge slot (2 edges/thread) --
__global__ void k_hist(const int* __restrict__ col, int* __restrict__ cnt,
                       unsigned short* __restrict__ seq) {
    int e2 = (blockIdx.x * 256 + threadIdx.x) * 2;
    if (e2 >= N_EDGES) return;
    int2 cc = *(const int2*)&col[e2];
    unsigned short s0 = (unsigned short)atomicAdd(&cnt[cc.x], 1);
    unsigned short s1 = (unsigned short)atomicAdd(&cnt[cc.y], 1);
    *(ushort2*)&seq[e2] = make_ushort2(s0, s1);
}

// ---------------- scan stage 1: per-1024-chunk sums ----------------
__global__ __launch_bounds__(256) void k_scan_red(const int* __restrict__ cnt,
                                                  int* __restrict__ part) {
    __shared__ int wsum[4];
    int i4 = blockIdx.x * SCAN_CHUNK + threadIdx.x * 4;
    int s;
    if (i4 + 3 < N_NODES) {
        int4 v = *(const int4*)&cnt[i4];
        s = v.x + v.y + v.z + v.w;
    } else {
        s = 0;
        #pragma unroll
        for (int j = 0; j < 4; ++j) if (i4 + j < N_NODES) s += cnt[i4 + j];
    }
    #pragma unroll
    for (int o = 32; o > 0; o >>= 1) s += __shfl_xor(s, o, 64);
    int lane = threadIdx.x & 63, w = threadIdx.x >> 6;
    if (lane == 0) wsum[w] = s;
    __syncthreads();
    if (threadIdx.x == 0) part[blockIdx.x] = wsum[0] + wsum[1] + wsum[2] + wsum[3];
}

// ---------------- scan stage 2 (merged): block offset + final rowptr + dis ----
__global__ __launch_bounds__(256) void k_scan_fin(const int* __restrict__ cnt,
                                                  const int* __restrict__ part,
                                                  int* __restrict__ rowptr,
                                                  float* __restrict__ dis) {
    __shared__ int wsum[4];
    __shared__ int sBase;
    int lane = threadIdx.x & 63, w = threadIdx.x >> 6;

    if (w == 0) {                         // wave 0: exclusive prefix of partials
        int v = (lane < SCAN_BLKS) ? part[lane] : 0;
        int s = v;
        #pragma unroll
        for (int o = 1; o < 64; o <<= 1) {
            int t = __shfl_up(s, o, 64);
            if (lane >= o) s += t;
        }
        if (lane == (int)blockIdx.x) sBase = s - v;   // SCAN_BLKS <= 64
    }

    int i4 = blockIdx.x * SCAN_CHUNK + threadIdx.x * 4;
    int v[4];
    #pragma unroll
    for (int j = 0; j < 4; ++j) v[j] = (i4 + j < N_NODES) ? cnt[i4 + j] : 0;
    int ts = v[0] + v[1] + v[2] + v[3];
    int incl = ts;
    #pragma unroll
    for (int o = 1; o < 64; o <<= 1) {
        int t = __shfl_up(incl, o, 64);
        if (lane >= o) incl += t;
    }
    if (lane == 63) wsum[w] = incl;
    __syncthreads();                      // covers sBase + wsum
    if (threadIdx.x == 0) {
        int a = 0;
        #pragma unroll
        for (int t = 0; t < 4; ++t) { int b = wsum[t]; wsum[t] = a; a += b; }
    }
    __syncthreads();
    int base = sBase + wsum[w] + (incl - ts);
    int pre = 0;
    #pragma unroll
    for (int j = 0; j < 4; ++j) {
        int i = i4 + j;
        if (i <= N_NODES) rowptr[i] = base + pre;
        if (i < N_NODES) dis[i] = rsqrtf((float)v[j] + 1.0f);   // +1 self loop
        pre += v[j];
    }
}

// ---------------- shared GEMM block body (f16 MFMA, fp8 out) ----------------
template <typename AIN>
__device__ __forceinline__ void gemm_block(int bid, const AIN* __restrict__ A,
                                           const unsigned short* __restrict__ WT,
                                           unsigned char* __restrict__ H,
                                           unsigned short* sWT) {
    for (int t = threadIdx.x; t < F * 16; t += 256) {
        int c = t >> 4, ch = t & 15;
        *(uint4*)&sWT[c * 136 + ch * 8] = *(const uint4*)&WT[(size_t)c * F + ch * 8];
    }
    __syncthreads();

    int wave = threadIdx.x >> 6, lane = threadIdx.x & 63;
    int m = lane & 15, q = lane >> 4;
    int row = bid * 64 + wave * 16 + m;
    int arow = (row < N_NODES) ? row : (N_NODES - 1);

    f32x4 acc[8];
    #pragma unroll
    for (int c = 0; c < 8; ++c) acc[c] = 0.f;

    #pragma unroll
    for (int kk = 0; kk < 4; ++kk) {
        int k0 = kk * 32 + q * 8;
        f16x8 a;
        if constexpr (sizeof(AIN) == 4) {
            const float* ap = &A[(size_t)arow * F + k0];
            float4 a0 = *(const float4*)ap;
            float4 a1 = *(const float4*)(ap + 4);
            a[0] = (_Float16)a0.x; a[1] = (_Float16)a0.y;
            a[2] = (_Float16)a0.z; a[3] = (_Float16)a0.w;
            a[4] = (_Float16)a1.x; a[5] = (_Float16)a1.y;
            a[6] = (_Float16)a1.z; a[7] = (_Float16)a1.w;
        } else {
            a = *(const f16x8*)&A[(size_t)arow * F + k0];
        }
        #pragma unroll
        for (int c = 0; c < 8; ++c) {
            f16x8 b = *(const f16x8*)&sWT[(c * 16 + m) * 136 + k0];
            acc[c] = __builtin_amdgcn_mfma_f32_16x16x32_f16(a, b, acc[c], 0, 0, 0);
        }
    }

    int rbase = bid * 64 + wave * 16 + q * 4;
    #pragma unroll
    for (int c = 0; c < 8; ++c) {
        #pragma unroll
        for (int r = 0; r < 4; ++r) {
            int rr = rbase + r;
            if (rr < N_NODES) H[(size_t)rr * F + c * 16 + m] = f2fp8(acc[c][r]);
        }
    }
}

// ---------------- GEMM layers 2/3 (f16 activations in) ----------------
__global__ __launch_bounds__(256) void k_gemm(const unsigned short* __restrict__ A,
                                              const unsigned short* __restrict__ WT,
                                              unsigned char* __restrict__ H) {
    __shared__ unsigned short sWT[F * 136];
    gemm_block<unsigned short>(blockIdx.x, A, WT, H, sWT);
}

// -------- fused: [gemm layer1 (f32 in)] || [CSR fill] in one dispatch --------
__global__ __launch_bounds__(256) void k_gemm1_fill(
        const float* __restrict__ A, const unsigned short* __restrict__ WT,
        unsigned char* __restrict__ H,
        const int* __restrict__ row, const int* __restrict__ col,
        const unsigned short* __restrict__ seq,
        const int* __restrict__ rowptr, const float* __restrict__ dis,
        unsigned* __restrict__ csr) {
    __shared__ unsigned short sWT[F * 136];
    if (blockIdx.x < GEMM_BLKS) {
        gemm_block<float>(blockIdx.x, A, WT, H, sWT);
        return;
    }
    int e2 = ((blockIdx.x - GEMM_BLKS) * 256 + threadIdx.x) * 2;
    if (e2 >= N_EDGES) return;
    int2 rr = *(const int2*)&row[e2];
    int2 cc = *(const int2*)&col[e2];
    ushort2 ss = *(const ushort2*)&seq[e2];
    int p0 = rowptr[cc.x] + (int)ss.x;
    csr[p0] = ((unsigned)rr.x << 16) | (unsigned)f2h16(dis[rr.x] * dis[cc.x]);
    int p1 = rowptr[cc.y] + (int)ss.y;
    csr[p1] = ((unsigned)rr.y << 16) | (unsigned)f2h16(dis[rr.y] * dis[cc.y]);
}

// ---------------- fused aggregate: wave-per-node CSR gather, fp8 rows ---------
// 64 lanes = 4 edge-groups x 16 lanes; 8 B (8 fp8 feats) per lane per gather.
// 8 edges in flight per group (depth 8, stride 32); pad entries -> norm 0.
template <typename OUT>   // ushort (f16 -> next GEMM) or float (final x3)
__global__ __launch_bounds__(256) void k_agg(const unsigned char* __restrict__ h,
                                             const float* __restrict__ dis,
                                             const int* __restrict__ rowptr,
                                             const unsigned* __restrict__ csr,
                                             const float* __restrict__ bias,
                                             const int* __restrict__ batch,
                                             OUT* __restrict__ xout,
                                             float* __restrict__ pool) {
    int wave = threadIdx.x >> 6;
    int lane = threadIdx.x & 63;
    int g = lane >> 4;          // edge group 0..3
    int l = lane & 15;          // feature slice: feats [8l, 8l+8)
    int node = blockIdx.x * 4 + wave;       // grid = 12500 exact

    float acc[8] = {0.f, 0.f, 0.f, 0.f, 0.f, 0.f, 0.f, 0.f};

    int s = rowptr[node], e = rowptr[node + 1];
    int i = s + g;
    unsigned c0 = (i      < e) ? csr[i]      : 0u;
    unsigned c1 = (i + 4  < e) ? csr[i + 4]  : 0u;
    unsigned c2 = (i + 8  < e) ? csr[i + 8]  : 0u;
    unsigned c3 = (i + 12 < e) ? csr[i + 12] : 0u;
    unsigned c4 = (i + 16 < e) ? csr[i + 16] : 0u;
    unsigned c5 = (i + 20 < e) ? csr[i + 20] : 0u;
    unsigned c6 = (i + 24 < e) ? csr[i + 24] : 0u;
    unsigned c7 = (i + 28 < e) ? csr[i + 28] : 0u;
    while (i < e) {
        unsigned long long v0 = *(const unsigned long long*)(h + (size_t)(c0 >> 16) * F + l * 8);
        unsigned long long v1 = *(const unsigned long long*)(h + (size_t)(c1 >> 16) * F + l * 8);
        unsigned long long v2 = *(const unsigned long long*)(h + (size_t)(c2 >> 16) * F + l * 8);
        unsigned long long v3 = *(const unsigned long long*)(h + (size_t)(c3 >> 16) * F + l * 8);
        unsigned long long v4 = *(const unsigned long long*)(h + (size_t)(c4 >> 16) * F + l * 8);
        unsigned long long v5 = *(const unsigned long long*)(h + (size_t)(c5 >> 16) * F + l * 8);
        unsigned long long v6 = *(const unsigned long long*)(h + (size_t)(c6 >> 16) * F + l * 8);
        unsigned long long v7 = *(const unsigned long long*)(h + (size_t)(c7 >> 16) * F + l * 8);
        float n0 = nrm_of(c0), n1 = nrm_of(c1), n2 = nrm_of(c2), n3 = nrm_of(c3);
        float n4 = nrm_of(c4), n5 = nrm_of(c5), n6 = nrm_of(c6), n7 = nrm_of(c7);
        c0 = (i + 32 < e) ? csr[i + 32] : 0u;
        c1 = (i + 36 < e) ? csr[i + 36] : 0u;
        c2 = (i + 40 < e) ? csr[i + 40] : 0u;
        c3 = (i + 44 < e) ? csr[i + 44] : 0u;
        c4 = (i + 48 < e) ? csr[i + 48] : 0u;
        c5 = (i + 52 < e) ? csr[i + 52] : 0u;
        c6 = (i + 56 < e) ? csr[i + 56] : 0u;
        c7 = (i + 60 < e) ? csr[i + 60] : 0u;
        fma8(acc, v0, n0); fma8(acc, v1, n1); fma8(acc, v2, n2); fma8(acc, v3, n3);
        fma8(acc, v4, n4); fma8(acc, v5, n5); fma8(acc, v6, n6); fma8(acc, v7, n7);
        i += 32;
    }

    // combine the 4 edge groups (butterfly over lane^16, lane^32)
    #pragma unroll
    for (int j = 0; j < 8; ++j) {
        acc[j] += __shfl_xor(acc[j], 16, 64);
        acc[j] += __shfl_xor(acc[j], 32, 64);
    }

    // self loop + bias + relu (all lanes; replicated across groups)
    float df = dis[node];
    unsigned long long sv = *(const unsigned long long*)(h + (size_t)node * F + l * 8);
    fma8(acc, sv, df * df);
    float4 ba = *(const float4*)&bias[l * 8];
    float4 bb = *(const float4*)&bias[l * 8 + 4];
    acc[0] = fmaxf(acc[0] + ba.x, 0.f);
    acc[1] = fmaxf(acc[1] + ba.y, 0.f);
    acc[2] = fmaxf(acc[2] + ba.z, 0.f);
    acc[3] = fmaxf(acc[3] + ba.w, 0.f);
    acc[4] = fmaxf(acc[4] + bb.x, 0.f);
    acc[5] = fmaxf(acc[5] + bb.y, 0.f);
    acc[6] = fmaxf(acc[6] + bb.z, 0.f);
    acc[7] = fmaxf(acc[7] + bb.w, 0.f);

    if (g == 0) {
        if constexpr (sizeof(OUT) == 2) {
            uint4 o;
            o.x = pkh2(acc[0], acc[1]);
            o.y = pkh2(acc[2], acc[3]);
            o.z = pkh2(acc[4], acc[5]);
            o.w = pkh2(acc[6], acc[7]);
            *(uint4*)&xout[(size_t)node * F + l * 8] = o;
        } else {
            *(float4*)&xout[(size_t)node * F + l * 8] =
                make_float4(acc[0], acc[1], acc[2], acc[3]);
            *(float4*)&xout[(size_t)node * F + l * 8 + 4] =
                make_float4(acc[4], acc[5], acc[6], acc[7]);
        }
    }

    // ---- pool: block LDS reduce (4 nodes) when same graph, else per-node ----
    __shared__ float red[4][F];
    __shared__ int gsh[4];
    if (lane == 0) gsh[wave] = batch[node];
    if (g == 0) {
        *(float4*)&red[wave][l * 8]     = make_float4(acc[0], acc[1], acc[2], acc[3]);
        *(float4*)&red[wave][l * 8 + 4] = make_float4(acc[4], acc[5], acc[6], acc[7]);
    }
    __syncthreads();
    int g0 = gsh[0];
    bool uni = (gsh[1] == g0) & (gsh[2] == g0) & (gsh[3] == g0);
    if (uni) {
        if (threadIdx.x < F) {
            float ssum = red[0][threadIdx.x] + red[1][threadIdx.x]
                       + red[2][threadIdx.x] + red[3][threadIdx.x];
            atomicAdd(&pool[(size_t)g0 * POOL_W + threadIdx.x], ssum);
        }
    } else if (g == 0) {
        int gg = gsh[wave];
        #pragma unroll
        for (int j = 0; j < 8; ++j)
            atomicAdd(&pool[(size_t)gg * POOL_W + l * 8 + j], acc[j]);
    }
}

extern "C" void kernel_launch(void* const* d_in, const int* in_sizes, int n_in,
                              void* d_out, int out_size, void* d_ws, size_t ws_size,
                              hipStream_t stream) {
    const float* x    = (const float*)d_in[0];
    const int*   erow = (const int*)d_in[1];
    const int*   ecol = erow + N_EDGES;
    const int*   batch= (const int*)d_in[2];
    const float* W0   = (const float*)d_in[3];
    const float* b0   = (const float*)d_in[4];
    const float* W1   = (const float*)d_in[5];
    const float* b1   = (const float*)d_in[6];
    const float* W2   = (const float*)d_in[7];
    const float* b2   = (const float*)d_in[8];

    float* pool = (float*)d_out;                  // [128, 384]
    float* x3   = (float*)d_out + NG * POOL_W;    // [50000, 128] fp32

    // ---- workspace carve-up (256B aligned) ----
    char* p = (char*)d_ws;
    auto carve = [&](size_t bytes) { char* q = p; p += (bytes + 255) & ~(size_t)255; return q; };
    float*          dis    = (float*)carve(N_NODES * 4);
    int*            cnt    = (int*)  carve(N_NODES * 4);
    int*            rowptr = (int*)  carve((N_NODES + 1) * 4);
    unsigned short* seq    = (unsigned short*)carve((size_t)N_EDGES * 2);
    int*            part   = (int*)  carve(SCAN_BLKS * 4);
    unsigned*       csr    = (unsigned*)carve((size_t)N_EDGES * 4);
    unsigned short* WT     = (unsigned short*)carve((size_t)3 * F * F * 2);
    unsigned char*  h      = (unsigned char*)carve((size_t)N_NODES * F);      // fp8
    unsigned short* B      = (unsigned short*)carve((size_t)N_NODES * F * 2); // f16

    const int nodeBlk  = (N_NODES + 255) / 256;       // 196
    const int aggBlk   = N_NODES / 4;                 // 12500 (exact)

    // ---- CSR build; layer-1 GEMM fused into the fill dispatch ----
    k_init<<<nodeBlk, 256, 0, stream>>>(cnt, pool, W0, W1, W2, WT);
    k_hist<<<EDGE2_BLKS, 256, 0, stream>>>(ecol, cnt, seq);
    k_scan_red<<<SCAN_BLKS, 256, 0, stream>>>(cnt, part);
    k_scan_fin<<<SCAN_BLKS, 256, 0, stream>>>(cnt, part, rowptr, dis);
    k_gemm1_fill<<<GEMM_BLKS + EDGE2_BLKS, 256, 0, stream>>>(
        x, WT + 0 * F * F, h, erow, ecol, seq, rowptr, dis, csr);

    // ---- layer 1 aggregate: h(fp8) -> B(f16) ----
    k_agg<unsigned short><<<aggBlk, 256, 0, stream>>>(h, dis, rowptr, csr, b0, batch, B, pool + 0 * F);

    // ---- layer 2: B -> h -> B ----
    k_gemm<<<GEMM_BLKS, 256, 0, stream>>>(B, WT + 1 * F * F, h);
    k_agg<unsigned short><<<aggBlk, 256, 0, stream>>>(h, dis, rowptr, csr, b1, batch, B, pool + 1 * F);

    // ---- layer 3: B -> h -> x3(f32, d_out) ----
    k_gemm<<<GEMM_BLKS, 256, 0, stream>>>(B, WT + 2 * F * F, h);
    k_agg<float><<<aggBlk, 256, 0, stream>>>(h, dis, rowptr, csr, b2, batch, x3, pool + 2 * F);
}

// Round 15
// 211.578 us; speedup vs baseline: 1.2042x; 1.0126x over previous
//
#include <hip/hip_runtime.h>
#include <hip/hip_fp16.h>

#define N_NODES 50000
#define N_EDGES 800000
#define F 128
#define NG 128
#define POOL_W (3*F)
#define SCAN_CHUNK 1024
#define SCAN_BLKS ((N_NODES + SCAN_CHUNK - 1) / SCAN_CHUNK)   // 49
#define GEMM_BLKS ((N_NODES + 63) / 64)                       // 782
#define EDGE2_BLKS ((N_EDGES / 2 + 255) / 256)                // 1563

typedef _Float16 f16x8 __attribute__((ext_vector_type(8)));
typedef float f32x2 __attribute__((ext_vector_type(2)));
typedef float f32x4 __attribute__((ext_vector_type(4)));

__device__ __forceinline__ unsigned short f2h16(float f) {
    return __half_as_ushort(__float2half_rn(f));
}
// pack two f32 -> two f16 in one u32 (v_cvt_pkrtz_f16_f32), type-safe bitcast
__device__ __forceinline__ unsigned pkh2(float a, float b) {
    auto v = __builtin_amdgcn_cvt_pkrtz(a, b);
    union { decltype(v) h; unsigned u; } t;
    t.h = v;
    return t.u;
}
// decode 8 fp8 (u64) and FMA into acc[0..7] with scalar n
__device__ __forceinline__ void fma8(float* acc, unsigned long long v, float n) {
    unsigned lo = (unsigned)v, hi = (unsigned)(v >> 32);
    f32x2 d;
    d = __builtin_amdgcn_cvt_pk_f32_fp8((int)lo, false);
    acc[0] = fmaf(n, d[0], acc[0]); acc[1] = fmaf(n, d[1], acc[1]);
    d = __builtin_amdgcn_cvt_pk_f32_fp8((int)lo, true);
    acc[2] = fmaf(n, d[0], acc[2]); acc[3] = fmaf(n, d[1], acc[3]);
    d = __builtin_amdgcn_cvt_pk_f32_fp8((int)hi, false);
    acc[4] = fmaf(n, d[0], acc[4]); acc[5] = fmaf(n, d[1], acc[5]);
    d = __builtin_amdgcn_cvt_pk_f32_fp8((int)hi, true);
    acc[6] = fmaf(n, d[0], acc[6]); acc[7] = fmaf(n, d[1], acc[7]);
}
__device__ __forceinline__ unsigned char f2fp8(float f) {
    return (unsigned char)(__builtin_amdgcn_cvt_pk_fp8_f32(f, f, 0, false) & 0xFF);
}
__device__ __forceinline__ float nrm_of(unsigned u) {
    return __half2float(__ushort_as_half((unsigned short)(u & 0xFFFFu)));
}

// ---------------- init: cnt=0, pool=0, WT = f16(W^T) x3 ----------------
__global__ void k_init(int* __restrict__ cnt, float* __restrict__ pool,
                       const float* __restrict__ W0, const float* __restrict__ W1,
                       const float* __restrict__ W2, unsigned short* __restrict__ WT) {
    int i = blockIdx.x * 256 + threadIdx.x;
    if (i < N_NODES) cnt[i] = 0;
    if (i < NG * POOL_W) {
        pool[i] = 0.0f;
        int w = i >> 14, r = i & 16383;          // 3*128*128 == NG*POOL_W
        int k = r >> 7, c = r & 127;
        const float* W = (w == 0) ? W0 : (w == 1) ? W1 : W2;
        WT[(size_t)w * F * F + c * F + k] = f2h16(W[r]);
    }
}

// ---------------- hist: cnt[col]++ and record per-edge slot (2 edges/thread) --
__global__ void k_hist(const int* __restrict__ col, int* __restrict__ cnt,
                       unsigned short* __restrict__ seq) {
    int e2 = (blockIdx.x * 256 + threadIdx.x) * 2;
    if (e2 >= N_EDGES) return;
    int2 cc = *(const int2*)&col[e2];
    unsigned short s0 = (unsigned short)atomicAdd(&cnt[cc.x], 1);
    unsigned short s1 = (unsigned short)atomicAdd(&cnt[cc.y], 1);
    *(ushort2*)&seq[e2] = make_ushort2(s0, s1);
}

// ---------------- scan stage 1: per-1024-chunk sums ----------------
__global__ __launch_bounds__(256) void k_scan_red(const int* __restrict__ cnt,
                                                  int* __restrict__ part) {
    __shared__ int wsum[4];
    int i4 = blockIdx.x * SCAN_CHUNK + threadIdx.x * 4;
    int s;
    if (i4 + 3 < N_NODES) {
        int4 v = *(const int4*)&cnt[i4];
        s = v.x + v.y + v.z + v.w;
    } else {
        s = 0;
        #pragma unroll
        for (int j = 0; j < 4; ++j) if (i4 + j < N_NODES) s += cnt[i4 + j];
    }
    #pragma unroll
    for (int o = 32; o > 0; o >>= 1) s += __shfl_xor(s, o, 64);
    int lane = threadIdx.x & 63, w = threadIdx.x >> 6;
    if (lane == 0) wsum[w] = s;
    __syncthreads();
    if (threadIdx.x == 0) part[blockIdx.x] = wsum[0] + wsum[1] + wsum[2] + wsum[3];
}

// ---------------- scan stage 2 (merged): block offset + final rowptr + dis ----
__global__ __launch_bounds__(256) void k_scan_fin(const int* __restrict__ cnt,
                                                  const int* __restrict__ part,
                                                  int* __restrict__ rowptr,
                                                  float* __restrict__ dis) {
    __shared__ int wsum[4];
    __shared__ int sBase;
    int lane = threadIdx.x & 63, w = threadIdx.x >> 6;

    if (w == 0) {                         // wave 0: exclusive prefix of partials
        int v = (lane < SCAN_BLKS) ? part[lane] : 0;
        int s = v;
        #pragma unroll
        for (int o = 1; o < 64; o <<= 1) {
            int t = __shfl_up(s, o, 64);
            if (lane >= o) s += t;
        }
        if (lane == (int)blockIdx.x) sBase = s - v;   // SCAN_BLKS <= 64
    }

    int i4 = blockIdx.x * SCAN_CHUNK + threadIdx.x * 4;
    int v[4];
    #pragma unroll
    for (int j = 0; j < 4; ++j) v[j] = (i4 + j < N_NODES) ? cnt[i4 + j] : 0;
    int ts = v[0] + v[1] + v[2] + v[3];
    int incl = ts;
    #pragma unroll
    for (int o = 1; o < 64; o <<= 1) {
        int t = __shfl_up(incl, o, 64);
        if (lane >= o) incl += t;
    }
    if (lane == 63) wsum[w] = incl;
    __syncthreads();                      // covers sBase + wsum
    if (threadIdx.x == 0) {
        int a = 0;
        #pragma unroll
        for (int t = 0; t < 4; ++t) { int b = wsum[t]; wsum[t] = a; a += b; }
    }
    __syncthreads();
    int base = sBase + wsum[w] + (incl - ts);
    int pre = 0;
    #pragma unroll
    for (int j = 0; j < 4; ++j) {
        int i = i4 + j;
        if (i <= N_NODES) rowptr[i] = base + pre;
        if (i < N_NODES) dis[i] = rsqrtf((float)v[j] + 1.0f);   // +1 self loop
        pre += v[j];
    }
}

// ---------------- shared GEMM block body (f16 MFMA, fp8 out) ----------------
template <typename AIN>
__device__ __forceinline__ void gemm_block(int bid, const AIN* __restrict__ A,
                                           const unsigned short* __restrict__ WT,
                                           unsigned char* __restrict__ H,
                                           unsigned short* sWT) {
    for (int t = threadIdx.x; t < F * 16; t += 256) {
        int c = t >> 4, ch = t & 15;
        *(uint4*)&sWT[c * 136 + ch * 8] = *(const uint4*)&WT[(size_t)c * F + ch * 8];
    }
    __syncthreads();

    int wave = threadIdx.x >> 6, lane = threadIdx.x & 63;
    int m = lane & 15, q = lane >> 4;
    int row = bid * 64 + wave * 16 + m;
    int arow = (row < N_NODES) ? row : (N_NODES - 1);

    f32x4 acc[8];
    #pragma unroll
    for (int c = 0; c < 8; ++c) acc[c] = 0.f;

    #pragma unroll
    for (int kk = 0; kk < 4; ++kk) {
        int k0 = kk * 32 + q * 8;
        f16x8 a;
        if constexpr (sizeof(AIN) == 4) {
            const float* ap = &A[(size_t)arow * F + k0];
            float4 a0 = *(const float4*)ap;
            float4 a1 = *(const float4*)(ap + 4);
            a[0] = (_Float16)a0.x; a[1] = (_Float16)a0.y;
            a[2] = (_Float16)a0.z; a[3] = (_Float16)a0.w;
            a[4] = (_Float16)a1.x; a[5] = (_Float16)a1.y;
            a[6] = (_Float16)a1.z; a[7] = (_Float16)a1.w;
        } else {
            a = *(const f16x8*)&A[(size_t)arow * F + k0];
        }
        #pragma unroll
        for (int c = 0; c < 8; ++c) {
            f16x8 b = *(const f16x8*)&sWT[(c * 16 + m) * 136 + k0];
            acc[c] = __builtin_amdgcn_mfma_f32_16x16x32_f16(a, b, acc[c], 0, 0, 0);
        }
    }

    int rbase = bid * 64 + wave * 16 + q * 4;
    #pragma unroll
    for (int c = 0; c < 8; ++c) {
        #pragma unroll
        for (int r = 0; r < 4; ++r) {
            int rr = rbase + r;
            if (rr < N_NODES) H[(size_t)rr * F + c * 16 + m] = f2fp8(acc[c][r]);
        }
    }
}

// ---------------- GEMM layers 2/3 (f16 activations in) ----------------
__global__ __launch_bounds__(256) void k_gemm(const unsigned short* __restrict__ A,
                                              const unsigned short* __restrict__ WT,
                                              unsigned char* __restrict__ H) {
    __shared__ unsigned short sWT[F * 136];
    gemm_block<unsigned short>(blockIdx.x, A, WT, H, sWT);
}

// -------- fused: [gemm layer1 (f32 in)] || [CSR fill] in one dispatch --------
__global__ __launch_bounds__(256) void k_gemm1_fill(
        const float* __restrict__ A, const unsigned short* __restrict__ WT,
        unsigned char* __restrict__ H,
        const int* __restrict__ row, const int* __restrict__ col,
        const unsigned short* __restrict__ seq,
        const int* __restrict__ rowptr, const float* __restrict__ dis,
        unsigned* __restrict__ csr) {
    __shared__ unsigned short sWT[F * 136];
    if (blockIdx.x < GEMM_BLKS) {
        gemm_block<float>(blockIdx.x, A, WT, H, sWT);
        return;
    }
    int e2 = ((blockIdx.x - GEMM_BLKS) * 256 + threadIdx.x) * 2;
    if (e2 >= N_EDGES) return;
    int2 rr = *(const int2*)&row[e2];
    int2 cc = *(const int2*)&col[e2];
    ushort2 ss = *(const ushort2*)&seq[e2];
    int p0 = rowptr[cc.x] + (int)ss.x;
    csr[p0] = ((unsigned)rr.x << 16) | (unsigned)f2h16(dis[rr.x] * dis[cc.x]);
    int p1 = rowptr[cc.y] + (int)ss.y;
    csr[p1] = ((unsigned)rr.y << 16) | (unsigned)f2h16(dis[rr.y] * dis[cc.y]);
}

// ---------------- fused aggregate: wave-per-node CSR gather, fp8 rows ---------
// 64 lanes = 4 edge-groups x 16 lanes; 8 B (8 fp8 feats) per lane per gather.
// 8 edges in flight per group (depth 8, stride 32); pad entries -> norm 0.
template <typename OUT>   // ushort (f16 -> next GEMM) or float (final x3)
__global__ __launch_bounds__(256) void k_agg(const unsigned char* __restrict__ h,
                                             const float* __restrict__ dis,
                                             const int* __restrict__ rowptr,
                                             const unsigned* __restrict__ csr,
                                             const float* __restrict__ bias,
                                             const int* __restrict__ batch,
                                             OUT* __restrict__ xout,
                                             float* __restrict__ pool) {
    int wave = threadIdx.x >> 6;
    int lane = threadIdx.x & 63;
    int g = lane >> 4;          // edge group 0..3
    int l = lane & 15;          // feature slice: feats [8l, 8l+8)
    int node = blockIdx.x * 4 + wave;       // grid = 12500 exact

    float acc[8] = {0.f, 0.f, 0.f, 0.f, 0.f, 0.f, 0.f, 0.f};

    int s = rowptr[node], e = rowptr[node + 1];
    int i = s + g;
    unsigned c0 = (i      < e) ? csr[i]      : 0u;
    unsigned c1 = (i + 4  < e) ? csr[i + 4]  : 0u;
    unsigned c2 = (i + 8  < e) ? csr[i + 8]  : 0u;
    unsigned c3 = (i + 12 < e) ? csr[i + 12] : 0u;
    unsigned c4 = (i + 16 < e) ? csr[i + 16] : 0u;
    unsigned c5 = (i + 20 < e) ? csr[i + 20] : 0u;
    unsigned c6 = (i + 24 < e) ? csr[i + 24] : 0u;
    unsigned c7 = (i + 28 < e) ? csr[i + 28] : 0u;
    while (i < e) {
        unsigned long long v0 = *(const unsigned long long*)(h + (size_t)(c0 >> 16) * F + l * 8);
        unsigned long long v1 = *(const unsigned long long*)(h + (size_t)(c1 >> 16) * F + l * 8);
        unsigned long long v2 = *(const unsigned long long*)(h + (size_t)(c2 >> 16) * F + l * 8);
        unsigned long long v3 = *(const unsigned long long*)(h + (size_t)(c3 >> 16) * F + l * 8);
        unsigned long long v4 = *(const unsigned long long*)(h + (size_t)(c4 >> 16) * F + l * 8);
        unsigned long long v5 = *(const unsigned long long*)(h + (size_t)(c5 >> 16) * F + l * 8);
        unsigned long long v6 = *(const unsigned long long*)(h + (size_t)(c6 >> 16) * F + l * 8);
        unsigned long long v7 = *(const unsigned long long*)(h + (size_t)(c7 >> 16) * F + l * 8);
        float n0 = nrm_of(c0), n1 = nrm_of(c1), n2 = nrm_of(c2), n3 = nrm_of(c3);
        float n4 = nrm_of(c4), n5 = nrm_of(c5), n6 = nrm_of(c6), n7 = nrm_of(c7);
        c0 = (i + 32 < e) ? csr[i + 32] : 0u;
        c1 = (i + 36 < e) ? csr[i + 36] : 0u;
        c2 = (i + 40 < e) ? csr[i + 40] : 0u;
        c3 = (i + 44 < e) ? csr[i + 44] : 0u;
        c4 = (i + 48 < e) ? csr[i + 48] : 0u;
        c5 = (i + 52 < e) ? csr[i + 52] : 0u;
        c6 = (i + 56 < e) ? csr[i + 56] : 0u;
        c7 = (i + 60 < e) ? csr[i + 60] : 0u;
        fma8(acc, v0, n0); fma8(acc, v1, n1); fma8(acc, v2, n2); fma8(acc, v3, n3);
        fma8(acc, v4, n4); fma8(acc, v5, n5); fma8(acc, v6, n6); fma8(acc, v7, n7);
        i += 32;
    }

    // combine the 4 edge groups (butterfly over lane^16, lane^32)
    #pragma unroll
    for (int j = 0; j < 8; ++j) {
        acc[j] += __shfl_xor(acc[j], 16, 64);
        acc[j] += __shfl_xor(acc[j], 32, 64);
    }

    // self loop + bias + relu (all lanes; replicated across groups)
    float df = dis[node];
    unsigned long long sv = *(const unsigned long long*)(h + (size_t)node * F + l * 8);
    fma8(acc, sv, df * df);
    float4 ba = *(const float4*)&bias[l * 8];
    float4 bb = *(const float4*)&bias[l * 8 + 4];
    acc[0] = fmaxf(acc[0] + ba.x, 0.f);
    acc[1] = fmaxf(acc[1] + ba.y, 0.f);
    acc[2] = fmaxf(acc[2] + ba.z, 0.f);
    acc[3] = fmaxf(acc[3] + ba.w, 0.f);
    acc[4] = fmaxf(acc[4] + bb.x, 0.f);
    acc[5] = fmaxf(acc[5] + bb.y, 0.f);
    acc[6] = fmaxf(acc[6] + bb.z, 0.f);
    acc[7] = fmaxf(acc[7] + bb.w, 0.f);

    if (g == 0) {
        if constexpr (sizeof(OUT) == 2) {
            uint4 o;
            o.x = pkh2(acc[0], acc[1]);
            o.y = pkh2(acc[2], acc[3]);
            o.z = pkh2(acc[4], acc[5]);
            o.w = pkh2(acc[6], acc[7]);
            *(uint4*)&xout[(size_t)node * F + l * 8] = o;
        } else {
            *(float4*)&xout[(size_t)node * F + l * 8] =
                make_float4(acc[0], acc[1], acc[2], acc[3]);
            *(float4*)&xout[(size_t)node * F + l * 8 + 4] =
                make_float4(acc[4], acc[5], acc[6], acc[7]);
        }
    }

    // ---- pool: block LDS reduce (4 nodes) when same graph, else per-node ----
    __shared__ float red[4][F];
    __shared__ int gsh[4];
    if (lane == 0) gsh[wave] = batch[node];
    if (g == 0) {
        *(float4*)&red[wave][l * 8]     = make_float4(acc[0], acc[1], acc[2], acc[3]);
        *(float4*)&red[wave][l * 8 + 4] = make_float4(acc[4], acc[5], acc[6], acc[7]);
    }
    __syncthreads();
    int g0 = gsh[0];
    bool uni = (gsh[1] == g0) & (gsh[2] == g0) & (gsh[3] == g0);
    if (uni) {
        if (threadIdx.x < F) {
            float ssum = red[0][threadIdx.x] + red[1][threadIdx.x]
                       + red[2][threadIdx.x] + red[3][threadIdx.x];
            atomicAdd(&pool[(size_t)g0 * POOL_W + threadIdx.x], ssum);
        }
    } else if (g == 0) {
        int gg = gsh[wave];
        #pragma unroll
        for (int j = 0; j < 8; ++j)
            atomicAdd(&pool[(size_t)gg * POOL_W + l * 8 + j], acc[j]);
    }
}

extern "C" void kernel_launch(void* const* d_in, const int* in_sizes, int n_in,
                              void* d_out, int out_size, void* d_ws, size_t ws_size,
                              hipStream_t stream) {
    const float* x    = (const float*)d_in[0];
    const int*   erow = (const int*)d_in[1];
    const int*   ecol = erow + N_EDGES;
    const int*   batch= (const int*)d_in[2];
    const float* W0   = (const float*)d_in[3];
    const float* b0   = (const float*)d_in[4];
    const float* W1   = (const float*)d_in[5];
    const float* b1   = (const float*)d_in[6];
    const float* W2   = (const float*)d_in[7];
    const float* b2   = (const float*)d_in[8];

    float* pool = (float*)d_out;                  // [128, 384]
    float* x3   = (float*)d_out + NG * POOL_W;    // [50000, 128] fp32

    // ---- workspace carve-up (256B aligned) ----
    char* p = (char*)d_ws;
    auto carve = [&](size_t bytes) { char* q = p; p += (bytes + 255) & ~(size_t)255; return q; };
    float*          dis    = (float*)carve(N_NODES * 4);
    int*            cnt    = (int*)  carve(N_NODES * 4);
    int*            rowptr = (int*)  carve((N_NODES + 1) * 4);
    unsigned short* seq    = (unsigned short*)carve((size_t)N_EDGES * 2);
    int*            part   = (int*)  carve(SCAN_BLKS * 4);
    unsigned*       csr    = (unsigned*)carve((size_t)N_EDGES * 4);
    unsigned short* WT     = (unsigned short*)carve((size_t)3 * F * F * 2);
    unsigned char*  h      = (unsigned char*)carve((size_t)N_NODES * F);      // fp8
    unsigned short* B      = (unsigned short*)carve((size_t)N_NODES * F * 2); // f16

    const int nodeBlk  = (N_NODES + 255) / 256;       // 196
    const int aggBlk   = N_NODES / 4;                 // 12500 (exact)

    // ---- CSR build; layer-1 GEMM fused into the fill dispatch ----
    k_init<<<nodeBlk, 256, 0, stream>>>(cnt, pool, W0, W1, W2, WT);
    k_hist<<<EDGE2_BLKS, 256, 0, stream>>>(ecol, cnt, seq);
    k_scan_red<<<SCAN_BLKS, 256, 0, stream>>>(cnt, part);
    k_scan_fin<<<SCAN_BLKS, 256, 0, stream>>>(cnt, part, rowptr, dis);
    k_gemm1_fill<<<GEMM_BLKS + EDGE2_BLKS, 256, 0, stream>>>(
        x, WT + 0 * F * F, h, erow, ecol, seq, rowptr, dis, csr);

    // ---- layer 1 aggregate: h(fp8) -> B(f16) ----
    k_agg<unsigned short><<<aggBlk, 256, 0, stream>>>(h, dis, rowptr, csr, b0, batch, B, pool + 0 * F);

    // ---- layer 2: B -> h -> B ----
    k_gemm<<<GEMM_BLKS, 256, 0, stream>>>(B, WT + 1 * F * F, h);
    k_agg<unsigned short><<<aggBlk, 256, 0, stream>>>(h, dis, rowptr, csr, b1, batch, B, pool + 1 * F);

    // ---- layer 3: B -> h -> x3(f32, d_out) ----
    k_gemm<<<GEMM_BLKS, 256, 0, stream>>>(B, WT + 2 * F * F, h);
    k_agg<float><<<aggBlk, 256, 0, stream>>>(h, dis, rowptr, csr, b2, batch, x3, pool + 2 * F);
}